// Round 15
// baseline (583.725 us; speedup 1.0000x reference)
//
#include <hip/hip_runtime.h>
#include <hip/hip_bf16.h>

typedef __hip_bfloat16 bf16;
typedef __attribute__((ext_vector_type(8))) short bf16x8;   // 8 bf16 (4 VGPRs)
typedef __attribute__((ext_vector_type(4))) float f32x4;    // MFMA accum

__device__ __forceinline__ float b2f(bf16 v) { return __bfloat162float(v); }
__device__ __forceinline__ bf16 f2b(float v) { return __float2bfloat16(v); }

// Scalar load/store from an external buffer whose dtype is decided by isb.
__device__ __forceinline__ float ldx(const void* p, size_t i, bool isb) {
    return isb ? b2f(((const bf16*)p)[i]) : ((const float*)p)[i];
}
__device__ __forceinline__ void stx(void* p, size_t i, bool isb, float v) {
    if (isb) ((bf16*)p)[i] = f2b(v);
    else     ((float*)p)[i] = v;
}
// Vector (8-elem) external load; i must be a multiple of 8.
__device__ __forceinline__ void ldx8(const void* p, size_t i, bool isb, float* o) {
    if (isb) {
        const bf16x8 v = *(const bf16x8*)((const bf16*)p + i);
#pragma unroll
        for (int j = 0; j < 8; j++) o[j] = b2f(((const bf16*)&v)[j]);
    } else {
        const float4 v0 = *(const float4*)((const float*)p + i);
        const float4 v1 = *(const float4*)((const float*)p + i + 4);
        o[0]=v0.x; o[1]=v0.y; o[2]=v0.z; o[3]=v0.w;
        o[4]=v1.x; o[5]=v1.y; o[6]=v1.z; o[7]=v1.w;
    }
}

// ---------------------------------------------------------------------------
// Dtype sniffer (verified round 3): decides fp32 vs bf16 external data.
// ---------------------------------------------------------------------------
__global__ void sniff_kernel(const void* __restrict__ x, int* __restrict__ flag) {
    const unsigned* w = (const unsigned*)x;
    const int t = threadIdx.x;
    int cnt = 0;
#pragma unroll
    for (int i = 0; i < 4; i++) {
        const unsigned word = w[t * 4 + i];
        const int e = (word >> 23) & 0xFF;
        cnt += (e >= 192) ? 1 : 0;
    }
    __shared__ int red[4];
#pragma unroll
    for (int o = 32; o > 0; o >>= 1) cnt += __shfl_down(cnt, o);
    if ((t & 63) == 0) red[t >> 6] = cnt;
    __syncthreads();
    if (t == 0) flag[0] = ((red[0] + red[1] + red[2] + red[3]) >= 512) ? 1 : 0;
}

// ---------------------------------------------------------------------------
// Merged PROLOGUE kernel (round-13 verified WIN): weight transposes (both
// phases) AND both input LNs in ONE dispatch. Block-uniform demux.
// ---------------------------------------------------------------------------
__global__ void prologue_kernel(
    const void* __restrict__ Wq,  const void* __restrict__ Wkv,
    const void* __restrict__ Wo,  const void* __restrict__ Wq2,
    const void* __restrict__ Wkv2, const void* __restrict__ Wo2,
    bf16* __restrict__ WTq,  bf16* __restrict__ WTkv,  bf16* __restrict__ WTo,
    bf16* __restrict__ WTq2, bf16* __restrict__ WTkv2, bf16* __restrict__ WTo2,
    const void* __restrict__ x, const void* __restrict__ ctx,
    const void* __restrict__ g1, const void* __restrict__ b1,
    const void* __restrict__ g2, const void* __restrict__ b2,
    const void* __restrict__ g3, const void* __restrict__ b3,
    bf16* __restrict__ outX, bf16* __restrict__ outB, bf16* __restrict__ outY,
    const int* __restrict__ flagp) {

    const bool isb = (*flagp != 0);
    const int bid = blockIdx.x;
    const int t = threadIdx.x;

    __shared__ __align__(16) char smem[16640];   // 64*65*4 = 16640 B

    if (bid < 2048) {
        // ================= wconv path (verified wconv8 body) =============
        float (*T)[65] = (float(*)[65])smem;
        const int bx = bid & 15, by = (bid >> 4) & 15, z = bid >> 8;
        const int zz = z & 3;
        const bool ca = z >= 4;
        const void* W = ca ? ((zz == 0) ? Wq2 : (zz == 3) ? Wo2 : Wkv2)
                           : ((zz == 0) ? Wq  : (zz == 3) ? Wo  : Wkv);
        bf16* Wt      = ca ? ((zz == 0) ? WTq2 : (zz == 3) ? WTo2 : WTkv2)
                           : ((zz == 0) ? WTq  : (zz == 3) ? WTo  : WTkv);
        const int N   = (zz == 1 || zz == 2) ? 2048 : 1024;
        const int K = 1024;
        const int n0 = bx * 64 + ((zz == 2) ? 1024 : 0);
        const int k0 = by * 64;
        const int rr = t >> 3, c8 = (t & 7) * 8;
#pragma unroll
        for (int i = 0; i < 2; i++) {
            const int row = rr + i * 32;
            float v[8];
            ldx8(W, (size_t)(k0 + row) * N + n0 + c8, isb, v);
#pragma unroll
            for (int j = 0; j < 8; j++) T[row][c8 + j] = v[j];
        }
        __syncthreads();
#pragma unroll
        for (int i = 0; i < 2; i++) {
            const int row = rr + i * 32;   // n-index within tile
            bf16x8 ov;
#pragma unroll
            for (int j = 0; j < 8; j++) ((bf16*)&ov)[j] = f2b(T[c8 + j][row]);
            *(bf16x8*)(Wt + (size_t)(n0 + row) * K + k0 + c8) = ov;
        }
        return;
    }

    // =================== LN path (verified ln_pro body) ==================
    const int F = 1024;
    float* red1 = (float*)smem;
    float* red2 = (float*)smem + 4;
    const int lnid = bid - 2048;             // 0..5119
    const int z = (lnid >= 2560) ? 1 : 0;
    const int bid2 = lnid - z * 2560;        // 0..2559
    const bool isCtx = bid2 >= 2048;
    const int row = isCtx ? bid2 - 2048 : bid2;
    const void* in = isCtx ? ctx : x;
    const size_t base = (isCtx ? (size_t)z * (512 * 1024)
                               : (size_t)z * (2048 * 1024)) + (size_t)row * F;

    float v[4];
    float s = 0.f;
#pragma unroll
    for (int i = 0; i < 4; i++) { v[i] = ldx(in, base + t + 256 * i, isb); s += v[i]; }

#pragma unroll
    for (int o = 32; o > 0; o >>= 1) s += __shfl_down(s, o);
    if ((t & 63) == 0) red1[t >> 6] = s;
    __syncthreads();
    const float mean = (red1[0] + red1[1] + red1[2] + red1[3]) * (1.0f / F);

    float ss = 0.f;
#pragma unroll
    for (int i = 0; i < 4; i++) { float d = v[i] - mean; ss += d * d; }
#pragma unroll
    for (int o = 32; o > 0; o >>= 1) ss += __shfl_down(ss, o);
    if ((t & 63) == 0) red2[t >> 6] = ss;
    __syncthreads();
    const float var = (red2[0] + red2[1] + red2[2] + red2[3]) * (1.0f / F);
    const float rn = rsqrtf(var + 1e-5f);

    if (isCtx) {
        const size_t obase = (size_t)z * (512 * 1024) + (size_t)row * F;
#pragma unroll
        for (int i = 0; i < 4; i++) {
            const int idx = t + 256 * i;
            const float nv = (v[i] - mean) * rn;
            outY[obase + idx] = f2b(nv * ldx(g3, idx, isb) + ldx(b3, idx, isb));
        }
    } else {
        const size_t obase = (size_t)z * (2048 * 1024) + (size_t)row * F;
#pragma unroll
        for (int i = 0; i < 4; i++) {
            const int idx = t + 256 * i;
            const float nv = (v[i] - mean) * rn;
            outX[obase + idx] = f2b(nv * ldx(g1, idx, isb) + ldx(b1, idx, isb));
            outB[obase + idx] = f2b(nv * ldx(g2, idx, isb) + ldx(b2, idx, isb));
        }
    }
}

// ---------------------------------------------------------------------------
// LayerNorm over F=1024, batch-fused via grid.z (per-batch strides in elems).
// Used for the mid-pipeline CA-x LN (and the fallback path).
// ---------------------------------------------------------------------------
__global__ void ln_dual_kernel(const void* __restrict__ in, size_t in_off, long in_bs,
                               int in_ext,
                               const void* __restrict__ g1, const void* __restrict__ b1,
                               const void* __restrict__ g2, const void* __restrict__ b2,
                               bf16* __restrict__ out1, bf16* __restrict__ out2,
                               long out_bs, const int* __restrict__ flagp) {
    const int F = 1024;
    const bool isb = (*flagp != 0);
    const bool inb = in_ext ? isb : true;
    const int row = blockIdx.x;
    const int z = blockIdx.z;
    const int t = threadIdx.x;
    const size_t base = in_off + (size_t)z * in_bs + (size_t)row * F;
    const size_t obase = (size_t)z * out_bs + (size_t)row * F;

    float v[4];
    float s = 0.f;
#pragma unroll
    for (int i = 0; i < 4; i++) { v[i] = ldx(in, base + t + 256 * i, inb); s += v[i]; }

    __shared__ float red1[4];
    __shared__ float red2[4];
#pragma unroll
    for (int o = 32; o > 0; o >>= 1) s += __shfl_down(s, o);
    if ((t & 63) == 0) red1[t >> 6] = s;
    __syncthreads();
    const float mean = (red1[0] + red1[1] + red1[2] + red1[3]) * (1.0f / F);

    float ss = 0.f;
#pragma unroll
    for (int i = 0; i < 4; i++) { float d = v[i] - mean; ss += d * d; }
#pragma unroll
    for (int o = 32; o > 0; o >>= 1) ss += __shfl_down(ss, o);
    if ((t & 63) == 0) red2[t >> 6] = ss;
    __syncthreads();
    const float var = (red2[0] + red2[1] + red2[2] + red2[3]) * (1.0f / F);
    const float rn = rsqrtf(var + 1e-5f);

#pragma unroll
    for (int i = 0; i < 4; i++) {
        const int idx = t + 256 * i;
        const float nv = (v[i] - mean) * rn;
        out1[obase + idx] = f2b(nv * ldx(g1, idx, isb) + ldx(b1, idx, isb));
        if (out2) out2[obase + idx] = f2b(nv * ldx(g2, idx, isb) + ldx(b2, idx, isb));
    }
}

// ---------------------------------------------------------------------------
// Grouped GEMM args. C = A[R,1024] @ Bt^T, 128x128 tile, BK=64, 4 waves.
// ---------------------------------------------------------------------------
struct GArgs {
    const bf16* A; const bf16* Bt; void* C;
    const void* bias; const void* res;
    bf16* kb0; bf16* kb1;
    int c_ext, res_ext, N, mode, zsplit, zrows, nbx, nby;
};

// ---------------------------------------------------------------------------
// Reg-staged grouped GEMM (verified body, padded LDS). Mode-1 V-half writes
// V^T via LDS transpose (round-8 win). Used for the BIG 3-slot dispatch at
// 128^2 tiles / 3.5 blocks/CU — round 11 proved 64^2 tiles REGRESS here.
// ---------------------------------------------------------------------------
__global__ __launch_bounds__(256) void gemm_fused(GArgs ga, GArgs gb, GArgs gc,
                                                  const int* __restrict__ flagp) {
    int bx = (int)blockIdx.x;
    GArgs g;
    if (bx < ga.nbx) { g = ga; }
    else if (bx < ga.nbx + gb.nbx) { g = gb; bx -= ga.nbx; }
    else { g = gc; bx -= ga.nbx + gb.nbx; }
    const int by = (int)blockIdx.y;
    if (by >= g.nby) return;               // block-uniform: no divergent barrier

    const int K = 1024;
    const bool isb = (*flagp != 0);

    __shared__ bf16 As[128][72];
    __shared__ bf16 Bs[128][72];

    const int t = threadIdx.x;
    const int w = t >> 6, lane = t & 63, li = lane & 15, quad = lane >> 4;
    const int wm = (w & 1) * 64, wn = (w >> 1) * 64;
    const int bm = by * 128, bn = bx * 128;

    f32x4 acc[4][4];
#pragma unroll
    for (int mi = 0; mi < 4; mi++)
#pragma unroll
        for (int ni = 0; ni < 4; ni++)
#pragma unroll
            for (int r = 0; r < 4; r++) acc[mi][ni][r] = 0.f;

    for (int k0 = 0; k0 < K; k0 += 64) {
#pragma unroll
        for (int c = 0; c < 4; c++) {
            const int d = c * 256 + t;
            const int row = d >> 3, ch = (d & 7) * 8;
            *(bf16x8*)&As[row][ch] = *(const bf16x8*)(g.A + (size_t)(bm + row) * K + k0 + ch);
            *(bf16x8*)&Bs[row][ch] = *(const bf16x8*)(g.Bt + (size_t)(bn + row) * K + k0 + ch);
        }
        __syncthreads();
#pragma unroll
        for (int kc = 0; kc < 2; kc++) {
            bf16x8 af[4], bfr[4];
#pragma unroll
            for (int i = 0; i < 4; i++) {
                af[i]  = *(const bf16x8*)&As[wm + i * 16 + li][kc * 32 + quad * 8];
                bfr[i] = *(const bf16x8*)&Bs[wn + i * 16 + li][kc * 32 + quad * 8];
            }
#pragma unroll
            for (int mi = 0; mi < 4; mi++)
#pragma unroll
                for (int ni = 0; ni < 4; ni++)
                    acc[mi][ni] = __builtin_amdgcn_mfma_f32_16x16x32_bf16(
                        af[mi], bfr[ni], acc[mi][ni], 0, 0, 0);
        }
        __syncthreads();
    }

    if (g.mode == 1) {
        if (bn >= 1024) {
            // -------- V block: LDS-transposed coalesced V^T store --------
            const int batch = (bm < g.zsplit) ? 0 : 1;
            bf16* kb = batch ? g.kb1 : g.kb0;
            const int brow = bm - batch * g.zsplit;
            const int vc0 = bn - 1024;
            bf16 (*T)[136] = (bf16(*)[136])&As[0][0];   // 64x136 fits in As
            const int c = t >> 2, seg = t & 3;           // c: V^T row, seg: 64B
#pragma unroll
            for (int p = 0; p < 2; p++) {
                if ((w >> 1) == p) {                     // waves owning cols p*64..
#pragma unroll
                    for (int mi = 0; mi < 4; mi++)
#pragma unroll
                        for (int ni = 0; ni < 4; ni++)
#pragma unroll
                            for (int r = 0; r < 4; r++)
                                T[ni * 16 + li][wm + mi * 16 + quad * 4 + r] =
                                    f2b(acc[mi][ni][r]);
                }
                __syncthreads();
                bf16* dst = kb + (size_t)1024 * g.zrows
                            + (size_t)(vc0 + p * 64 + c) * g.zrows + brow + seg * 32;
#pragma unroll
                for (int j = 0; j < 4; j++)
                    *(bf16x8*)(dst + j * 8) = *(const bf16x8*)&T[c][seg * 32 + j * 8];
                __syncthreads();
            }
            return;
        }
        // -------- K block: verified coalesced row-major store --------
#pragma unroll
        for (int mi = 0; mi < 4; mi++)
#pragma unroll
            for (int r = 0; r < 4; r++) {
                const int row = bm + wm + mi * 16 + quad * 4 + r;
                bf16* kb = (row < g.zsplit) ? g.kb0 : g.kb1;
                const int lrow = (row < g.zsplit) ? row : row - g.zsplit;
#pragma unroll
                for (int ni = 0; ni < 4; ni++) {
                    const int col = bn + wn + ni * 16 + li;
                    kb[(size_t)lrow * 1024 + col] = f2b(acc[mi][ni][r]);
                }
            }
        return;
    }

#pragma unroll
    for (int mi = 0; mi < 4; mi++)
#pragma unroll
        for (int r = 0; r < 4; r++) {
            const int row = bm + wm + mi * 16 + quad * 4 + r;
#pragma unroll
            for (int ni = 0; ni < 4; ni++) {
                const int col = bn + wn + ni * 16 + li;
                float v = acc[mi][ni][r];
                if (g.bias) v += ldx(g.bias, col, isb);
                if (g.res)  v += ldx(g.res, (size_t)row * g.N + col, g.res_ext ? isb : true);
                stx(g.C, (size_t)row * g.N + col, g.c_ext ? isb : true, v);
            }
        }
}

// ---------------------------------------------------------------------------
// Round-10 verified: 64x64-tile mode-0 GEMM for the three standalone GEMMs
// (SA-oproj, CA-q, CA-oproj), grid (16,64) = 4 blocks/CU. WIN: −21.6 µs.
// ---------------------------------------------------------------------------
__global__ __launch_bounds__(256) void gemm_t64(
    const bf16* __restrict__ A, const bf16* __restrict__ Bt,
    void* __restrict__ C, int c_ext,
    const void* __restrict__ bias,
    const void* __restrict__ res, int res_ext, int N,
    const int* __restrict__ flagp) {

    const int K = 1024;
    const bool isb = (*flagp != 0);

    __shared__ bf16 As[64][72];
    __shared__ bf16 Bs[64][72];

    const int t = threadIdx.x;
    const int w = t >> 6, lane = t & 63, li = lane & 15, quad = lane >> 4;
    const int wm = (w & 1) * 32, wn = (w >> 1) * 32;
    const int bm = blockIdx.y * 64, bn = blockIdx.x * 64;

    f32x4 acc[2][2];
#pragma unroll
    for (int mi = 0; mi < 2; mi++)
#pragma unroll
        for (int ni = 0; ni < 2; ni++)
#pragma unroll
            for (int r = 0; r < 4; r++) acc[mi][ni][r] = 0.f;

    for (int k0 = 0; k0 < K; k0 += 64) {
#pragma unroll
        for (int c = 0; c < 2; c++) {
            const int d = c * 256 + t;
            const int row = d >> 3, ch = (d & 7) * 8;
            *(bf16x8*)&As[row][ch] = *(const bf16x8*)(A + (size_t)(bm + row) * K + k0 + ch);
            *(bf16x8*)&Bs[row][ch] = *(const bf16x8*)(Bt + (size_t)(bn + row) * K + k0 + ch);
        }
        __syncthreads();
#pragma unroll
        for (int kc = 0; kc < 2; kc++) {
            bf16x8 af[2], bfr[2];
#pragma unroll
            for (int mi = 0; mi < 2; mi++)
                af[mi] = *(const bf16x8*)&As[wm + mi * 16 + li][kc * 32 + quad * 8];
#pragma unroll
            for (int ni = 0; ni < 2; ni++)
                bfr[ni] = *(const bf16x8*)&Bs[wn + ni * 16 + li][kc * 32 + quad * 8];
#pragma unroll
            for (int mi = 0; mi < 2; mi++)
#pragma unroll
                for (int ni = 0; ni < 2; ni++)
                    acc[mi][ni] = __builtin_amdgcn_mfma_f32_16x16x32_bf16(
                        af[mi], bfr[ni], acc[mi][ni], 0, 0, 0);
        }
        __syncthreads();
    }

#pragma unroll
    for (int mi = 0; mi < 2; mi++)
#pragma unroll
        for (int r = 0; r < 4; r++) {
            const int row = bm + wm + mi * 16 + quad * 4 + r;
#pragma unroll
            for (int ni = 0; ni < 2; ni++) {
                const int col = bn + wn + ni * 16 + li;
                float v = acc[mi][ni][r];
                if (bias) v += ldx(bias, col, isb);
                if (res)  v += ldx(res, (size_t)row * N + col, res_ext ? isb : true);
                stx(C, (size_t)row * N + col, c_ext ? isb : true, v);
            }
        }
}

// ---------------------------------------------------------------------------
// Slow-path MFMA GEMM (round-7 verified, used only if workspace is small).
// ---------------------------------------------------------------------------
__global__ __launch_bounds__(256) void gemm_mfma(
    const bf16* __restrict__ A, long a_bs, const void* __restrict__ W,
    void* __restrict__ C, size_t c_off, long c_bs, int c_ext,
    const void* __restrict__ bias,
    const void* __restrict__ res, size_t res_off, long res_bs, int res_ext,
    int K, int N, int mode, int R,
    bf16* __restrict__ kb0, bf16* __restrict__ kb1,
    const int* __restrict__ flagp) {

    const bool isb = (*flagp != 0);
    const bool resb = res_ext ? isb : true;
    const bool cb = c_ext ? isb : true;
    const int z = blockIdx.z;

    const bf16* Az = A + (size_t)z * a_bs;
    const size_t coz = c_off + (size_t)z * c_bs;
    const size_t roz = res_off + (size_t)z * res_bs;

    __shared__ bf16 As[64][72];
    __shared__ bf16 Bs[64][72];

    const int t = threadIdx.x;
    const int w = t >> 6, lane = t & 63, li = lane & 15, quad = lane >> 4;
    const int wm = (w & 1) * 32, wn = (w >> 1) * 32;
    const int bm = blockIdx.y * 64, bn = blockIdx.x * 64;

    f32x4 acc[2][2];
#pragma unroll
    for (int mi = 0; mi < 2; mi++)
#pragma unroll
        for (int ni = 0; ni < 2; ni++)
#pragma unroll
            for (int r = 0; r < 4; r++) acc[mi][ni][r] = 0.f;

    for (int k0 = 0; k0 < K; k0 += 64) {
#pragma unroll
        for (int c = 0; c < 2; c++) {
            const int lin = t * 16 + c * 8;
            const int row = lin >> 6, kk = lin & 63;
            *(bf16x8*)&As[row][kk] = *(const bf16x8*)(Az + (size_t)(bm + row) * K + k0 + kk);
        }
#pragma unroll
        for (int c = 0; c < 2; c++) {
            const int lin = t * 16 + c * 8;
            const int kk = lin >> 6, n0 = lin & 63;
            float v[8];
            ldx8(W, (size_t)(k0 + kk) * N + bn + n0, isb, v);
            const int st = t & 7;
#pragma unroll
            for (int i = 0; i < 8; i++) {
                const int ii = (i + st) & 7;
                Bs[n0 + ii][kk] = f2b(v[ii]);
            }
        }
        __syncthreads();
#pragma unroll
        for (int kc = 0; kc < 2; kc++) {
            bf16x8 af[2], bfr[2];
#pragma unroll
            for (int mi = 0; mi < 2; mi++)
                af[mi] = *(const bf16x8*)&As[wm + mi * 16 + li][kc * 32 + quad * 8];
#pragma unroll
            for (int ni = 0; ni < 2; ni++)
                bfr[ni] = *(const bf16x8*)&Bs[wn + ni * 16 + li][kc * 32 + quad * 8];
#pragma unroll
            for (int mi = 0; mi < 2; mi++)
#pragma unroll
                for (int ni = 0; ni < 2; ni++)
                    acc[mi][ni] = __builtin_amdgcn_mfma_f32_16x16x32_bf16(
                        af[mi], bfr[ni], acc[mi][ni], 0, 0, 0);
        }
        __syncthreads();
    }

    if (mode == 1) {
        bf16* kb = z ? kb1 : kb0;
#pragma unroll
        for (int mi = 0; mi < 2; mi++)
#pragma unroll
            for (int r = 0; r < 4; r++) {
                const int row = bm + wm + mi * 16 + quad * 4 + r;
#pragma unroll
                for (int ni = 0; ni < 2; ni++) {
                    const int col = bn + wn + ni * 16 + li;
                    const float v = acc[mi][ni][r];
                    if (col < 1024)
                        kb[(size_t)row * 1024 + col] = f2b(v);
                    else
                        kb[(size_t)1024 * R + (size_t)(col - 1024) * R + row] = f2b(v);
                }
            }
        return;
    }

#pragma unroll
    for (int mi = 0; mi < 2; mi++)
#pragma unroll
        for (int r = 0; r < 4; r++) {
            const int row = bm + wm + mi * 16 + quad * 4 + r;
#pragma unroll
            for (int ni = 0; ni < 2; ni++) {
                const int col = bn + wn + ni * 16 + li;
                float v = acc[mi][ni][r];
                if (bias) v += ldx(bias, col, isb);
                if (res)  v += ldx(res, roz + (size_t)row * N + col, resb);
                stx(C, coz + (size_t)row * N + col, cb, v);
            }
        }
}

// ---------------------------------------------------------------------------
// attn_flash: round-0 verified 1-wave body. Used by the fallback path.
// ---------------------------------------------------------------------------
__global__ __launch_bounds__(64) void attn_flash(
    const bf16* __restrict__ qb, const bf16* __restrict__ kv0,
    const bf16* __restrict__ kv1,
    const void* __restrict__ rel_emb, bf16* __restrict__ out,
    long qo_bs, long out_bs, int m, int rel_off, const int* __restrict__ flagp) {

    const float SC = 0.125f * 1.44269504f;
    const bool isb = (*flagp != 0);
    const int id = blockIdx.x;
    const int xcd = id & 7;
    const int slot = id >> 3;
    const int c = (slot >> 6) * 8 + xcd;
    const int h = c & 15, z = c >> 4;
    const int q0 = (slot & 63) * 32;
    const int t = threadIdx.x;
    const int li = t & 15, quad = t >> 4;

    const bf16* qz = qb + (size_t)z * qo_bs;
    bf16* oz = out + (size_t)z * out_bs;
    const bf16* kb = z ? kv1 : kv0;
    const bf16* vtb = kb + (size_t)m * 1024;

    __shared__ float bias_s[32];
    __shared__ float tab[2080];
    __shared__ bf16 Ps[16][40];

    if (t < 32) bias_s[t] = ldx(rel_emb, t * 16 + h, isb) * SC - 40.0f;
    __syncthreads();

    const int tsz = m + 31;
    for (int i = t; i < tsz; i += 64) {
        const int rel = i - 31 - q0 + rel_off;
        const int ab = rel < 0 ? -rel : rel;
        int bucket = rel >= 0 ? 16 : 0;
        if (ab < 8) {
            bucket += ab;
        } else {
            const int p = 31 - __clz(ab);
            const int k2 = 2 * p + ((ab * ab >= (1 << (2 * p + 1))) ? 1 : 0);
            const int val = k2 + 2;
            bucket += (val > 15) ? 15 : val;
        }
        tab[i] = bias_s[bucket];
    }
    __syncthreads();

    bf16x8 aq[2][2];
#pragma unroll
    for (int g = 0; g < 2; g++)
#pragma unroll
        for (int kc = 0; kc < 2; kc++)
            aq[g][kc] = *(const bf16x8*)(qz + (size_t)(q0 + g * 16 + li) * 1024
                                         + h * 64 + kc * 32 + quad * 8);

    bf16x8 ones;
#pragma unroll
    for (int j = 0; j < 8; j++) ((short*)&ones)[j] = 0x3F80;

    f32x4 o[2][4], lac[2];
#pragma unroll
    for (int g = 0; g < 2; g++) {
#pragma unroll
        for (int r = 0; r < 4; r++) lac[g][r] = 0.f;
#pragma unroll
        for (int nb = 0; nb < 4; nb++)
#pragma unroll
            for (int r = 0; r < 4; r++) o[g][nb][r] = 0.f;
    }

    for (int j0 = 0; j0 < m; j0 += 32) {
        bf16x8 kf[4], vf[4];
#pragma unroll
        for (int nb = 0; nb < 2; nb++)
#pragma unroll
            for (int kc = 0; kc < 2; kc++)
                kf[nb * 2 + kc] = *(const bf16x8*)(
                    kb + (size_t)(j0 + nb * 16 + li) * 1024 + h * 64 + kc * 32 + quad * 8);
#pragma unroll
        for (int nb = 0; nb < 4; nb++)
            vf[nb] = *(const bf16x8*)(
                vtb + (size_t)(h * 64 + nb * 16 + li) * m + j0 + quad * 8);

#pragma unroll
        for (int g = 0; g < 2; g++) {
            f32x4 s[2];
            __builtin_amdgcn_s_setprio(1);
#pragma unroll
            for (int nb = 0; nb < 2; nb++) {
                f32x4 a;
#pragma unroll
                for (int r = 0; r < 4; r++) a[r] = 0.f;
#pragma unroll
                for (int kc = 0; kc < 2; kc++)
                    a = __builtin_amdgcn_mfma_f32_16x16x32_bf16(aq[g][kc], kf[nb * 2 + kc],
                                                                a, 0, 0, 0);
                s[nb] = a;
            }
            __builtin_amdgcn_s_setprio(0);
#pragma unroll
            for (int nb = 0; nb < 2; nb++)
#pragma unroll
                for (int r = 0; r < 4; r++) {
                    const int ti = j0 + nb * 16 + li + 31 - (g * 16 + quad * 4 + r);
                    s[nb][r] = exp2f(fmaf(s[nb][r], SC, tab[ti]));
                }
#pragma unroll
            for (int nb = 0; nb < 2; nb++)
#pragma unroll
                for (int r = 0; r < 4; r++)
                    Ps[quad * 4 + r][nb * 16 + li] = f2b(s[nb][r]);
            const bf16x8 ap = *(const bf16x8*)&Ps[li][quad * 8];
            __builtin_amdgcn_s_setprio(1);
#pragma unroll
            for (int nb = 0; nb < 4; nb++)
                o[g][nb] = __builtin_amdgcn_mfma_f32_16x16x32_bf16(ap, vf[nb],
                                                                   o[g][nb], 0, 0, 0);
            lac[g] = __builtin_amdgcn_mfma_f32_16x16x32_bf16(ap, ones, lac[g], 0, 0, 0);
            __builtin_amdgcn_s_setprio(0);
        }
    }

#pragma unroll
    for (int g = 0; g < 2; g++)
#pragma unroll
        for (int r = 0; r < 4; r++) {
            const float inv = 1.0f / lac[g][r];
            const int qi = q0 + g * 16 + quad * 4 + r;
#pragma unroll
            for (int nb = 0; nb < 4; nb++)
                oz[(size_t)qi * 1024 + h * 64 + nb * 16 + li] = f2b(o[g][nb][r] * inv);
        }
}

// ---------------------------------------------------------------------------
// ROUND 15: attn_flash16 — 16 queries per wave (g-loop removed), 4
// independent waves/block, zero barriers. Round-14 post-mortem found the
// occupancy experiment was never run: every variant offered exactly 2048
// waves (32 q/wave fixes the work-unit count). Halving the q-tile doubles
// work units: 4096 waves = 1024 blocks x 4 = 4 blocks/CU = 16 waves/CU
// offered (LDS 38.7 KB -> 4 blocks/CU fits; VGPR drops ~16). Cost: K/V
// fetch doubles (L2-resident, measured benign in round 14) and per-wave
// load:compute worsens 2x — covered if doubled TLP materializes.
// Falsification: occupancy still ~21% -> per-CU pin is structural; revert.
// ---------------------------------------------------------------------------
__global__ __launch_bounds__(256) void attn_flash16(
    const bf16* __restrict__ qb, const bf16* __restrict__ kv0,
    const bf16* __restrict__ kv1,
    const void* __restrict__ rel_emb, bf16* __restrict__ out,
    long qo_bs, long out_bs, int m, int rel_off, const int* __restrict__ flagp) {

    const float SC = 0.125f * 1.44269504f;
    const bool isb = (*flagp != 0);
    const int t256 = threadIdx.x;
    const int w = t256 >> 6;                  // wave id 0..3
    const int t = t256 & 63;                  // lane
    const int id = (int)blockIdx.x * 4 + w;   // 0..4095
    const int xcd = id & 7;
    const int slot = id >> 3;                 // 0..511
    const int c = (slot >> 7) * 8 + xcd;      // 0..31
    const int h = c & 15, z = c >> 4;
    const int q0 = (slot & 127) * 16;         // 16-query tiles
    const int li = t & 15, quad = t >> 4;

    const bf16* qz = qb + (size_t)z * qo_bs;
    bf16* oz = out + (size_t)z * out_bs;
    const bf16* kb = z ? kv1 : kv0;
    const bf16* vtb = kb + (size_t)m * 1024;

    // Per-wave private LDS slices (no block barriers anywhere).
    __shared__ float tabS[4][2064];           // covers m+15 <= 2063
    __shared__ float biasS[4][32];
    __shared__ bf16  PsS[4][16][40];
    float* tab = tabS[w];
    float* bias_s = biasS[w];
    bf16 (*Ps)[40] = PsS[w];

    if (t < 32) bias_s[t] = ldx(rel_emb, t * 16 + h, isb) * SC - 40.0f;
    // wave-internal LDS RAW: compiler-inserted lgkmcnt (verified Ps pattern)

    const int tsz = m + 15;
    for (int i = t; i < tsz; i += 64) {
        const int rel = i - 15 - q0 + rel_off;
        const int ab = rel < 0 ? -rel : rel;
        int bucket = rel >= 0 ? 16 : 0;
        if (ab < 8) {
            bucket += ab;
        } else {
            const int p = 31 - __clz(ab);
            const int k2 = 2 * p + ((ab * ab >= (1 << (2 * p + 1))) ? 1 : 0);
            const int val = k2 + 2;
            bucket += (val > 15) ? 15 : val;
        }
        tab[i] = bias_s[bucket];
    }

    bf16x8 aq[2];
#pragma unroll
    for (int kc = 0; kc < 2; kc++)
        aq[kc] = *(const bf16x8*)(qz + (size_t)(q0 + li) * 1024
                                  + h * 64 + kc * 32 + quad * 8);

    bf16x8 ones;
#pragma unroll
    for (int j = 0; j < 8; j++) ((short*)&ones)[j] = 0x3F80;

    f32x4 o[4], lac;
#pragma unroll
    for (int r = 0; r < 4; r++) lac[r] = 0.f;
#pragma unroll
    for (int nb = 0; nb < 4; nb++)
#pragma unroll
        for (int r = 0; r < 4; r++) o[nb][r] = 0.f;

    for (int j0 = 0; j0 < m; j0 += 32) {
        bf16x8 kf[4], vf[4];
#pragma unroll
        for (int nb = 0; nb < 2; nb++)
#pragma unroll
            for (int kc = 0; kc < 2; kc++)
                kf[nb * 2 + kc] = *(const bf16x8*)(
                    kb + (size_t)(j0 + nb * 16 + li) * 1024 + h * 64 + kc * 32 + quad * 8);
#pragma unroll
        for (int nb = 0; nb < 4; nb++)
            vf[nb] = *(const bf16x8*)(
                vtb + (size_t)(h * 64 + nb * 16 + li) * m + j0 + quad * 8);

        f32x4 s[2];
        __builtin_amdgcn_s_setprio(1);
#pragma unroll
        for (int nb = 0; nb < 2; nb++) {
            f32x4 a;
#pragma unroll
            for (int r = 0; r < 4; r++) a[r] = 0.f;
#pragma unroll
            for (int kc = 0; kc < 2; kc++)
                a = __builtin_amdgcn_mfma_f32_16x16x32_bf16(aq[kc], kf[nb * 2 + kc],
                                                            a, 0, 0, 0);
            s[nb] = a;
        }
        __builtin_amdgcn_s_setprio(0);
#pragma unroll
        for (int nb = 0; nb < 2; nb++)
#pragma unroll
            for (int r = 0; r < 4; r++) {
                const int ti = j0 + nb * 16 + li + 15 - (quad * 4 + r);
                s[nb][r] = exp2f(fmaf(s[nb][r], SC, tab[ti]));
            }
#pragma unroll
        for (int nb = 0; nb < 2; nb++)
#pragma unroll
            for (int r = 0; r < 4; r++)
                Ps[quad * 4 + r][nb * 16 + li] = f2b(s[nb][r]);
        const bf16x8 ap = *(const bf16x8*)&Ps[li][quad * 8];
        __builtin_amdgcn_s_setprio(1);
#pragma unroll
        for (int nb = 0; nb < 4; nb++)
            o[nb] = __builtin_amdgcn_mfma_f32_16x16x32_bf16(ap, vf[nb], o[nb], 0, 0, 0);
        lac = __builtin_amdgcn_mfma_f32_16x16x32_bf16(ap, ones, lac, 0, 0, 0);
        __builtin_amdgcn_s_setprio(0);
    }

#pragma unroll
    for (int r = 0; r < 4; r++) {
        const float inv = 1.0f / lac[r];
        const int qi = q0 + quad * 4 + r;
#pragma unroll
        for (int nb = 0; nb < 4; nb++)
            oz[(size_t)qi * 1024 + h * 64 + nb * 16 + li] = f2b(o[nb][r] * inv);
    }
}

// ---------------------------------------------------------------------------
// Launcher. Fast path (ws >= 56 MB + 256; measured ws = 256 MB):
//   F_A|F_B|F_C (24 MB) + WT (8) + F_X (8) + F_Y (6) + WT2 (8) = 54 MB.
// Round-14 schedule (best: 448.0 µs) with attn on attn_flash16 (16 q/wave,
// 4096 waves = 16 waves/CU offered). Fallback: round-7 plan (24 MB).
// ---------------------------------------------------------------------------
extern "C" void kernel_launch(void* const* d_in, const int* in_sizes, int n_in,
                              void* d_out, int out_size, void* d_ws, size_t ws_size,
                              hipStream_t stream) {
    const long M1 = 1024 * 1024;
    const long M2 = 2 * 1024 * 1024;
    const long M4 = 4 * 1024 * 1024;
    if (ws_size < 24u * 1024 * 1024 + 256) return;

    const void* x      = d_in[0];
    const void* ctx    = d_in[1];
    const void* sa_ng  = d_in[2];
    const void* sa_nb  = d_in[3];
    const void* sa_ncg = d_in[4];
    const void* sa_ncb = d_in[5];
    const void* sa_wq  = d_in[6];
    const void* sa_wkv = d_in[7];
    const void* sa_wo  = d_in[8];
    const void* sa_bo  = d_in[9];
    const void* sa_rel = d_in[10];
    const void* ca_ng  = d_in[11];
    const void* ca_nb  = d_in[12];
    const void* ca_ncg = d_in[13];
    const void* ca_ncb = d_in[14];
    const void* ca_wq  = d_in[15];
    const void* ca_wkv = d_in[16];
    const void* ca_wo  = d_in[17];
    const void* ca_bo  = d_in[18];
    const void* ca_rel = d_in[19];

    int* flag = (int*)d_ws;
    bf16* F_A = (bf16*)((char*)d_ws + 256);
    bf16* F_B = F_A + M4;
    bf16* F_C = F_B + M4;
    bf16* WT  = F_C + M4;                // fast path only (SA weights)
    bf16* F_X = WT + M4;                 // fast path only (xn buffer)
    bf16* F_Y = F_X + M4;                // fast path only (ctx-LN + CA K/V)
    bf16* WT2 = F_Y + 3 * M1;            // fast path only (CA weights)
    bf16* qd  = (bf16*)d_out;            // d_out as bf16 scratch (q / ao)

    sniff_kernel<<<1, 256, 0, stream>>>(x, flag);

    if (ws_size >= 56u * 1024 * 1024 + 256) {
        bf16* WTq  = WT;                 // [1024][1024]
        bf16* WTkv = WT + M1;            // [2048][1024]
        bf16* WTo  = WT + 3 * M1;        // [1024][1024]
        bf16* WT2q  = WT2;
        bf16* WT2kv = WT2 + M1;
        bf16* WT2o  = WT2 + 3 * M1;
        bf16* CAK0 = F_Y + M1;           // z0: K[512][1024] + V^T[1024][512]
        bf16* CAK1 = F_Y + 2 * M1;       // z1: same layout

        // ===== prologue: weight transposes + both input LNs (ONE dispatch)
        prologue_kernel<<<dim3(7168), 256, 0, stream>>>(
            sa_wq, sa_wkv, sa_wo, ca_wq, ca_wkv, ca_wo,
            WTq, WTkv, WTo, WT2q, WT2kv, WT2o,
            x, ctx, sa_ng, sa_nb, sa_ncg, sa_ncb, ca_ncg, ca_ncb,
            F_X, F_B, F_Y, flag);

        // ===== BIG (128^2): SA-q + SA-kv + CA-kv =====
        {
            GArgs gq = {};
            gq.A = F_X; gq.Bt = WTq; gq.C = qd;
            gq.N = 1024; gq.nbx = 8; gq.nby = 32;
            GArgs gkv = {};
            gkv.A = F_B; gkv.Bt = WTkv;
            gkv.N = 2048; gkv.mode = 1; gkv.zsplit = 2048; gkv.zrows = 2048;
            gkv.kb0 = F_A; gkv.kb1 = F_C; gkv.nbx = 16; gkv.nby = 32;
            GArgs gca = {};
            gca.A = F_Y; gca.Bt = WT2kv;
            gca.N = 2048; gca.mode = 1; gca.zsplit = 512; gca.zrows = 512;
            gca.kb0 = CAK0; gca.kb1 = CAK1; gca.nbx = 16; gca.nby = 8;
            gemm_fused<<<dim3(40, 32), 256, 0, stream>>>(gq, gkv, gca, flag);
        }

        // ===== self-attention + o-proj =====
        attn_flash16<<<dim3(1024), 256, 0, stream>>>(
            qd, F_A, F_C, sa_rel, qd, M2, M2, 2048, 0, flag);
        gemm_t64<<<dim3(16, 64), 256, 0, stream>>>(
            qd, WTo, F_B, 0, sa_bo, x, 1, 1024, flag);

        // ===== cross-attention =====
        ln_dual_kernel<<<dim3(2048, 1, 2), 256, 0, stream>>>(
            F_B, 0, M2, 0, ca_ng, ca_nb, nullptr, nullptr, F_X, nullptr, M2, flag);
        gemm_t64<<<dim3(16, 64), 256, 0, stream>>>(
            F_X, WT2q, qd, 0, nullptr, nullptr, 0, 1024, flag);
        attn_flash16<<<dim3(1024), 256, 0, stream>>>(
            qd, CAK0, CAK1, ca_rel, F_C, M2, M2, 512, 1536, flag);
        gemm_t64<<<dim3(16, 64), 256, 0, stream>>>(
            F_C, WT2o, d_out, 1, ca_bo, F_B, 0, 1024, flag);
        return;
    }

    // ================= fallback: round-7 verified plan =================
    ln_dual_kernel<<<dim3(2048, 1, 2), 256, 0, stream>>>(
        x, 0, M2, 1, sa_ng, sa_nb, sa_ncg, sa_ncb, F_A, F_B, M2, flag);
    gemm_mfma<<<dim3(16, 32, 2), 256, 0, stream>>>(
        F_A, M2, sa_wq, qd, 0, M2, 0, nullptr, nullptr, 0, 0, 0,
        1024, 1024, 0, 0, nullptr, nullptr, flag);
    gemm_mfma<<<dim3(32, 32, 2), 256, 0, stream>>>(
        F_B, M2, sa_wkv, nullptr, 0, 0, 0, nullptr, nullptr, 0, 0, 0,
        1024, 2048, 1, 2048, F_A, F_C, flag);
    attn_flash<<<dim3(2048), 64, 0, stream>>>(
        qd, F_A, F_C, sa_rel, qd, M2, M2, 2048, 0, flag);
    gemm_mfma<<<dim3(16, 32, 2), 256, 0, stream>>>(
        qd, M2, sa_wo, F_B, 0, M2, 0, sa_bo, x, 0, M2, 1,
        1024, 1024, 0, 0, nullptr, nullptr, flag);

    ln_dual_kernel<<<dim3(2048, 1, 2), 256, 0, stream>>>(
        F_B, 0, M2, 0, ca_ng, ca_nb, nullptr, nullptr, F_A, nullptr, M2, flag);
    ln_dual_kernel<<<dim3(512, 1, 2), 256, 0, stream>>>(
        ctx, 0, 512 * 1024, 1, ca_ncg, ca_ncb, nullptr, nullptr,
        F_C, nullptr, 512 * 1024, flag);
    gemm_mfma<<<dim3(16, 32, 2), 256, 0, stream>>>(
        F_A, M2, ca_wq, qd, 0, M2, 0, nullptr, nullptr, 0, 0, 0,
        1024, 1024, 0, 0, nullptr, nullptr, flag);
    gemm_mfma<<<dim3(32, 8, 2), 256, 0, stream>>>(
        F_C, 512 * 1024, ca_wkv, nullptr, 0, 0, 0, nullptr, nullptr, 0, 0, 0,
        1024, 2048, 1, 512, F_A, F_A + M1, flag);
    attn_flash<<<dim3(2048), 64, 0, stream>>>(
        qd, F_A, F_A + M1, ca_rel, F_C, M2, M2, 512, 1536, flag);
    gemm_mfma<<<dim3(16, 32, 2), 256, 0, stream>>>(
        F_C, M2, ca_wo, d_out, 0, M2, 1, ca_bo, F_B, 0, M2, 0,
        1024, 1024, 0, 0, nullptr, nullptr, flag);
}

// Round 17
// 440.659 us; speedup vs baseline: 1.3247x; 1.3247x over previous
//
#include <hip/hip_runtime.h>
#include <hip/hip_bf16.h>

typedef __hip_bfloat16 bf16;
typedef __attribute__((ext_vector_type(8))) short bf16x8;   // 8 bf16 (4 VGPRs)
typedef __attribute__((ext_vector_type(4))) float f32x4;    // MFMA accum

__device__ __forceinline__ float b2f(bf16 v) { return __bfloat162float(v); }
__device__ __forceinline__ bf16 f2b(float v) { return __float2bfloat16(v); }

// Scalar load/store from an external buffer whose dtype is decided by isb.
__device__ __forceinline__ float ldx(const void* p, size_t i, bool isb) {
    return isb ? b2f(((const bf16*)p)[i]) : ((const float*)p)[i];
}
__device__ __forceinline__ void stx(void* p, size_t i, bool isb, float v) {
    if (isb) ((bf16*)p)[i] = f2b(v);
    else     ((float*)p)[i] = v;
}
// Vector (8-elem) external load; i must be a multiple of 8.
__device__ __forceinline__ void ldx8(const void* p, size_t i, bool isb, float* o) {
    if (isb) {
        const bf16x8 v = *(const bf16x8*)((const bf16*)p + i);
#pragma unroll
        for (int j = 0; j < 8; j++) o[j] = b2f(((const bf16*)&v)[j]);
    } else {
        const float4 v0 = *(const float4*)((const float*)p + i);
        const float4 v1 = *(const float4*)((const float*)p + i + 4);
        o[0]=v0.x; o[1]=v0.y; o[2]=v0.z; o[3]=v0.w;
        o[4]=v1.x; o[5]=v1.y; o[6]=v1.z; o[7]=v1.w;
    }
}

// ---------------------------------------------------------------------------
// Dtype sniffer (verified round 3): decides fp32 vs bf16 external data.
// ---------------------------------------------------------------------------
__global__ void sniff_kernel(const void* __restrict__ x, int* __restrict__ flag) {
    const unsigned* w = (const unsigned*)x;
    const int t = threadIdx.x;
    int cnt = 0;
#pragma unroll
    for (int i = 0; i < 4; i++) {
        const unsigned word = w[t * 4 + i];
        const int e = (word >> 23) & 0xFF;
        cnt += (e >= 192) ? 1 : 0;
    }
    __shared__ int red[4];
#pragma unroll
    for (int o = 32; o > 0; o >>= 1) cnt += __shfl_down(cnt, o);
    if ((t & 63) == 0) red[t >> 6] = cnt;
    __syncthreads();
    if (t == 0) flag[0] = ((red[0] + red[1] + red[2] + red[3]) >= 512) ? 1 : 0;
}

// ---------------------------------------------------------------------------
// Merged PROLOGUE kernel (round-13 verified WIN): weight transposes (both
// phases) AND both input LNs in ONE dispatch. Block-uniform demux.
// ---------------------------------------------------------------------------
__global__ void prologue_kernel(
    const void* __restrict__ Wq,  const void* __restrict__ Wkv,
    const void* __restrict__ Wo,  const void* __restrict__ Wq2,
    const void* __restrict__ Wkv2, const void* __restrict__ Wo2,
    bf16* __restrict__ WTq,  bf16* __restrict__ WTkv,  bf16* __restrict__ WTo,
    bf16* __restrict__ WTq2, bf16* __restrict__ WTkv2, bf16* __restrict__ WTo2,
    const void* __restrict__ x, const void* __restrict__ ctx,
    const void* __restrict__ g1, const void* __restrict__ b1,
    const void* __restrict__ g2, const void* __restrict__ b2,
    const void* __restrict__ g3, const void* __restrict__ b3,
    bf16* __restrict__ outX, bf16* __restrict__ outB, bf16* __restrict__ outY,
    const int* __restrict__ flagp) {

    const bool isb = (*flagp != 0);
    const int bid = blockIdx.x;
    const int t = threadIdx.x;

    __shared__ __align__(16) char smem[16640];   // 64*65*4 = 16640 B

    if (bid < 2048) {
        // ================= wconv path (verified wconv8 body) =============
        float (*T)[65] = (float(*)[65])smem;
        const int bx = bid & 15, by = (bid >> 4) & 15, z = bid >> 8;
        const int zz = z & 3;
        const bool ca = z >= 4;
        const void* W = ca ? ((zz == 0) ? Wq2 : (zz == 3) ? Wo2 : Wkv2)
                           : ((zz == 0) ? Wq  : (zz == 3) ? Wo  : Wkv);
        bf16* Wt      = ca ? ((zz == 0) ? WTq2 : (zz == 3) ? WTo2 : WTkv2)
                           : ((zz == 0) ? WTq  : (zz == 3) ? WTo  : WTkv);
        const int N   = (zz == 1 || zz == 2) ? 2048 : 1024;
        const int K = 1024;
        const int n0 = bx * 64 + ((zz == 2) ? 1024 : 0);
        const int k0 = by * 64;
        const int rr = t >> 3, c8 = (t & 7) * 8;
#pragma unroll
        for (int i = 0; i < 2; i++) {
            const int row = rr + i * 32;
            float v[8];
            ldx8(W, (size_t)(k0 + row) * N + n0 + c8, isb, v);
#pragma unroll
            for (int j = 0; j < 8; j++) T[row][c8 + j] = v[j];
        }
        __syncthreads();
#pragma unroll
        for (int i = 0; i < 2; i++) {
            const int row = rr + i * 32;   // n-index within tile
            bf16x8 ov;
#pragma unroll
            for (int j = 0; j < 8; j++) ((bf16*)&ov)[j] = f2b(T[c8 + j][row]);
            *(bf16x8*)(Wt + (size_t)(n0 + row) * K + k0 + c8) = ov;
        }
        return;
    }

    // =================== LN path (verified ln_pro body) ==================
    const int F = 1024;
    float* red1 = (float*)smem;
    float* red2 = (float*)smem + 4;
    const int lnid = bid - 2048;             // 0..5119
    const int z = (lnid >= 2560) ? 1 : 0;
    const int bid2 = lnid - z * 2560;        // 0..2559
    const bool isCtx = bid2 >= 2048;
    const int row = isCtx ? bid2 - 2048 : bid2;
    const void* in = isCtx ? ctx : x;
    const size_t base = (isCtx ? (size_t)z * (512 * 1024)
                               : (size_t)z * (2048 * 1024)) + (size_t)row * F;

    float v[4];
    float s = 0.f;
#pragma unroll
    for (int i = 0; i < 4; i++) { v[i] = ldx(in, base + t + 256 * i, isb); s += v[i]; }

#pragma unroll
    for (int o = 32; o > 0; o >>= 1) s += __shfl_down(s, o);
    if ((t & 63) == 0) red1[t >> 6] = s;
    __syncthreads();
    const float mean = (red1[0] + red1[1] + red1[2] + red1[3]) * (1.0f / F);

    float ss = 0.f;
#pragma unroll
    for (int i = 0; i < 4; i++) { float d = v[i] - mean; ss += d * d; }
#pragma unroll
    for (int o = 32; o > 0; o >>= 1) ss += __shfl_down(ss, o);
    if ((t & 63) == 0) red2[t >> 6] = ss;
    __syncthreads();
    const float var = (red2[0] + red2[1] + red2[2] + red2[3]) * (1.0f / F);
    const float rn = rsqrtf(var + 1e-5f);

    if (isCtx) {
        const size_t obase = (size_t)z * (512 * 1024) + (size_t)row * F;
#pragma unroll
        for (int i = 0; i < 4; i++) {
            const int idx = t + 256 * i;
            const float nv = (v[i] - mean) * rn;
            outY[obase + idx] = f2b(nv * ldx(g3, idx, isb) + ldx(b3, idx, isb));
        }
    } else {
        const size_t obase = (size_t)z * (2048 * 1024) + (size_t)row * F;
#pragma unroll
        for (int i = 0; i < 4; i++) {
            const int idx = t + 256 * i;
            const float nv = (v[i] - mean) * rn;
            outX[obase + idx] = f2b(nv * ldx(g1, idx, isb) + ldx(b1, idx, isb));
            outB[obase + idx] = f2b(nv * ldx(g2, idx, isb) + ldx(b2, idx, isb));
        }
    }
}

// ---------------------------------------------------------------------------
// LayerNorm over F=1024, batch-fused via grid.z (per-batch strides in elems).
// Used for the mid-pipeline CA-x LN (and the fallback path).
// ---------------------------------------------------------------------------
__global__ void ln_dual_kernel(const void* __restrict__ in, size_t in_off, long in_bs,
                               int in_ext,
                               const void* __restrict__ g1, const void* __restrict__ b1,
                               const void* __restrict__ g2, const void* __restrict__ b2,
                               bf16* __restrict__ out1, bf16* __restrict__ out2,
                               long out_bs, const int* __restrict__ flagp) {
    const int F = 1024;
    const bool isb = (*flagp != 0);
    const bool inb = in_ext ? isb : true;
    const int row = blockIdx.x;
    const int z = blockIdx.z;
    const int t = threadIdx.x;
    const size_t base = in_off + (size_t)z * in_bs + (size_t)row * F;
    const size_t obase = (size_t)z * out_bs + (size_t)row * F;

    float v[4];
    float s = 0.f;
#pragma unroll
    for (int i = 0; i < 4; i++) { v[i] = ldx(in, base + t + 256 * i, inb); s += v[i]; }

    __shared__ float red1[4];
    __shared__ float red2[4];
#pragma unroll
    for (int o = 32; o > 0; o >>= 1) s += __shfl_down(s, o);
    if ((t & 63) == 0) red1[t >> 6] = s;
    __syncthreads();
    const float mean = (red1[0] + red1[1] + red1[2] + red1[3]) * (1.0f / F);

    float ss = 0.f;
#pragma unroll
    for (int i = 0; i < 4; i++) { float d = v[i] - mean; ss += d * d; }
#pragma unroll
    for (int o = 32; o > 0; o >>= 1) ss += __shfl_down(ss, o);
    if ((t & 63) == 0) red2[t >> 6] = ss;
    __syncthreads();
    const float var = (red2[0] + red2[1] + red2[2] + red2[3]) * (1.0f / F);
    const float rn = rsqrtf(var + 1e-5f);

#pragma unroll
    for (int i = 0; i < 4; i++) {
        const int idx = t + 256 * i;
        const float nv = (v[i] - mean) * rn;
        out1[obase + idx] = f2b(nv * ldx(g1, idx, isb) + ldx(b1, idx, isb));
        if (out2) out2[obase + idx] = f2b(nv * ldx(g2, idx, isb) + ldx(b2, idx, isb));
    }
}

// ---------------------------------------------------------------------------
// Grouped GEMM args. C = A[R,1024] @ Bt^T, 128x128 tile, BK=64, 4 waves.
// ---------------------------------------------------------------------------
struct GArgs {
    const bf16* A; const bf16* Bt; void* C;
    const void* bias; const void* res;
    bf16* kb0; bf16* kb1;
    int c_ext, res_ext, N, mode, zsplit, zrows, nbx, nby;
};

// ---------------------------------------------------------------------------
// Reg-staged grouped GEMM (verified body, padded LDS). Mode-1 V-half writes
// V^T via LDS transpose (round-8 win). Used for the BIG 3-slot dispatch at
// 128^2 tiles / 3.5 blocks/CU — round 11 proved 64^2 tiles REGRESS here.
// ---------------------------------------------------------------------------
__global__ __launch_bounds__(256) void gemm_fused(GArgs ga, GArgs gb, GArgs gc,
                                                  const int* __restrict__ flagp) {
    int bx = (int)blockIdx.x;
    GArgs g;
    if (bx < ga.nbx) { g = ga; }
    else if (bx < ga.nbx + gb.nbx) { g = gb; bx -= ga.nbx; }
    else { g = gc; bx -= ga.nbx + gb.nbx; }
    const int by = (int)blockIdx.y;
    if (by >= g.nby) return;               // block-uniform: no divergent barrier

    const int K = 1024;
    const bool isb = (*flagp != 0);

    __shared__ bf16 As[128][72];
    __shared__ bf16 Bs[128][72];

    const int t = threadIdx.x;
    const int w = t >> 6, lane = t & 63, li = lane & 15, quad = lane >> 4;
    const int wm = (w & 1) * 64, wn = (w >> 1) * 64;
    const int bm = by * 128, bn = bx * 128;

    f32x4 acc[4][4];
#pragma unroll
    for (int mi = 0; mi < 4; mi++)
#pragma unroll
        for (int ni = 0; ni < 4; ni++)
#pragma unroll
            for (int r = 0; r < 4; r++) acc[mi][ni][r] = 0.f;

    for (int k0 = 0; k0 < K; k0 += 64) {
#pragma unroll
        for (int c = 0; c < 4; c++) {
            const int d = c * 256 + t;
            const int row = d >> 3, ch = (d & 7) * 8;
            *(bf16x8*)&As[row][ch] = *(const bf16x8*)(g.A + (size_t)(bm + row) * K + k0 + ch);
            *(bf16x8*)&Bs[row][ch] = *(const bf16x8*)(g.Bt + (size_t)(bn + row) * K + k0 + ch);
        }
        __syncthreads();
#pragma unroll
        for (int kc = 0; kc < 2; kc++) {
            bf16x8 af[4], bfr[4];
#pragma unroll
            for (int i = 0; i < 4; i++) {
                af[i]  = *(const bf16x8*)&As[wm + i * 16 + li][kc * 32 + quad * 8];
                bfr[i] = *(const bf16x8*)&Bs[wn + i * 16 + li][kc * 32 + quad * 8];
            }
#pragma unroll
            for (int mi = 0; mi < 4; mi++)
#pragma unroll
                for (int ni = 0; ni < 4; ni++)
                    acc[mi][ni] = __builtin_amdgcn_mfma_f32_16x16x32_bf16(
                        af[mi], bfr[ni], acc[mi][ni], 0, 0, 0);
        }
        __syncthreads();
    }

    if (g.mode == 1) {
        if (bn >= 1024) {
            // -------- V block: LDS-transposed coalesced V^T store --------
            const int batch = (bm < g.zsplit) ? 0 : 1;
            bf16* kb = batch ? g.kb1 : g.kb0;
            const int brow = bm - batch * g.zsplit;
            const int vc0 = bn - 1024;
            bf16 (*T)[136] = (bf16(*)[136])&As[0][0];   // 64x136 fits in As
            const int c = t >> 2, seg = t & 3;           // c: V^T row, seg: 64B
#pragma unroll
            for (int p = 0; p < 2; p++) {
                if ((w >> 1) == p) {                     // waves owning cols p*64..
#pragma unroll
                    for (int mi = 0; mi < 4; mi++)
#pragma unroll
                        for (int ni = 0; ni < 4; ni++)
#pragma unroll
                            for (int r = 0; r < 4; r++)
                                T[ni * 16 + li][wm + mi * 16 + quad * 4 + r] =
                                    f2b(acc[mi][ni][r]);
                }
                __syncthreads();
                bf16* dst = kb + (size_t)1024 * g.zrows
                            + (size_t)(vc0 + p * 64 + c) * g.zrows + brow + seg * 32;
#pragma unroll
                for (int j = 0; j < 4; j++)
                    *(bf16x8*)(dst + j * 8) = *(const bf16x8*)&T[c][seg * 32 + j * 8];
                __syncthreads();
            }
            return;
        }
        // -------- K block: verified coalesced row-major store --------
#pragma unroll
        for (int mi = 0; mi < 4; mi++)
#pragma unroll
            for (int r = 0; r < 4; r++) {
                const int row = bm + wm + mi * 16 + quad * 4 + r;
                bf16* kb = (row < g.zsplit) ? g.kb0 : g.kb1;
                const int lrow = (row < g.zsplit) ? row : row - g.zsplit;
#pragma unroll
                for (int ni = 0; ni < 4; ni++) {
                    const int col = bn + wn + ni * 16 + li;
                    kb[(size_t)lrow * 1024 + col] = f2b(acc[mi][ni][r]);
                }
            }
        return;
    }

#pragma unroll
    for (int mi = 0; mi < 4; mi++)
#pragma unroll
        for (int r = 0; r < 4; r++) {
            const int row = bm + wm + mi * 16 + quad * 4 + r;
#pragma unroll
            for (int ni = 0; ni < 4; ni++) {
                const int col = bn + wn + ni * 16 + li;
                float v = acc[mi][ni][r];
                if (g.bias) v += ldx(g.bias, col, isb);
                if (g.res)  v += ldx(g.res, (size_t)row * g.N + col, g.res_ext ? isb : true);
                stx(g.C, (size_t)row * g.N + col, g.c_ext ? isb : true, v);
            }
        }
}

// ---------------------------------------------------------------------------
// Round-10 verified: 64x64-tile mode-0 GEMM for the three standalone GEMMs
// (SA-oproj, CA-q, CA-oproj), grid (16,64) = 4 blocks/CU. WIN: −21.6 µs.
// ---------------------------------------------------------------------------
__global__ __launch_bounds__(256) void gemm_t64(
    const bf16* __restrict__ A, const bf16* __restrict__ Bt,
    void* __restrict__ C, int c_ext,
    const void* __restrict__ bias,
    const void* __restrict__ res, int res_ext, int N,
    const int* __restrict__ flagp) {

    const int K = 1024;
    const bool isb = (*flagp != 0);

    __shared__ bf16 As[64][72];
    __shared__ bf16 Bs[64][72];

    const int t = threadIdx.x;
    const int w = t >> 6, lane = t & 63, li = lane & 15, quad = lane >> 4;
    const int wm = (w & 1) * 32, wn = (w >> 1) * 32;
    const int bm = blockIdx.y * 64, bn = blockIdx.x * 64;

    f32x4 acc[2][2];
#pragma unroll
    for (int mi = 0; mi < 2; mi++)
#pragma unroll
        for (int ni = 0; ni < 2; ni++)
#pragma unroll
            for (int r = 0; r < 4; r++) acc[mi][ni][r] = 0.f;

    for (int k0 = 0; k0 < K; k0 += 64) {
#pragma unroll
        for (int c = 0; c < 2; c++) {
            const int d = c * 256 + t;
            const int row = d >> 3, ch = (d & 7) * 8;
            *(bf16x8*)&As[row][ch] = *(const bf16x8*)(A + (size_t)(bm + row) * K + k0 + ch);
            *(bf16x8*)&Bs[row][ch] = *(const bf16x8*)(Bt + (size_t)(bn + row) * K + k0 + ch);
        }
        __syncthreads();
#pragma unroll
        for (int kc = 0; kc < 2; kc++) {
            bf16x8 af[2], bfr[2];
#pragma unroll
            for (int mi = 0; mi < 2; mi++)
                af[mi] = *(const bf16x8*)&As[wm + mi * 16 + li][kc * 32 + quad * 8];
#pragma unroll
            for (int ni = 0; ni < 2; ni++)
                bfr[ni] = *(const bf16x8*)&Bs[wn + ni * 16 + li][kc * 32 + quad * 8];
#pragma unroll
            for (int mi = 0; mi < 2; mi++)
#pragma unroll
                for (int ni = 0; ni < 2; ni++)
                    acc[mi][ni] = __builtin_amdgcn_mfma_f32_16x16x32_bf16(
                        af[mi], bfr[ni], acc[mi][ni], 0, 0, 0);
        }
        __syncthreads();
    }

#pragma unroll
    for (int mi = 0; mi < 2; mi++)
#pragma unroll
        for (int r = 0; r < 4; r++) {
            const int row = bm + wm + mi * 16 + quad * 4 + r;
#pragma unroll
            for (int ni = 0; ni < 2; ni++) {
                const int col = bn + wn + ni * 16 + li;
                float v = acc[mi][ni][r];
                if (bias) v += ldx(bias, col, isb);
                if (res)  v += ldx(res, (size_t)row * N + col, res_ext ? isb : true);
                stx(C, (size_t)row * N + col, c_ext ? isb : true, v);
            }
        }
}

// ---------------------------------------------------------------------------
// Slow-path MFMA GEMM (round-7 verified, used only if workspace is small).
// ---------------------------------------------------------------------------
__global__ __launch_bounds__(256) void gemm_mfma(
    const bf16* __restrict__ A, long a_bs, const void* __restrict__ W,
    void* __restrict__ C, size_t c_off, long c_bs, int c_ext,
    const void* __restrict__ bias,
    const void* __restrict__ res, size_t res_off, long res_bs, int res_ext,
    int K, int N, int mode, int R,
    bf16* __restrict__ kb0, bf16* __restrict__ kb1,
    const int* __restrict__ flagp) {

    const bool isb = (*flagp != 0);
    const bool resb = res_ext ? isb : true;
    const bool cb = c_ext ? isb : true;
    const int z = blockIdx.z;

    const bf16* Az = A + (size_t)z * a_bs;
    const size_t coz = c_off + (size_t)z * c_bs;
    const size_t roz = res_off + (size_t)z * res_bs;

    __shared__ bf16 As[64][72];
    __shared__ bf16 Bs[64][72];

    const int t = threadIdx.x;
    const int w = t >> 6, lane = t & 63, li = lane & 15, quad = lane >> 4;
    const int wm = (w & 1) * 32, wn = (w >> 1) * 32;
    const int bm = blockIdx.y * 64, bn = blockIdx.x * 64;

    f32x4 acc[2][2];
#pragma unroll
    for (int mi = 0; mi < 2; mi++)
#pragma unroll
        for (int ni = 0; ni < 2; ni++)
#pragma unroll
            for (int r = 0; r < 4; r++) acc[mi][ni][r] = 0.f;

    for (int k0 = 0; k0 < K; k0 += 64) {
#pragma unroll
        for (int c = 0; c < 2; c++) {
            const int lin = t * 16 + c * 8;
            const int row = lin >> 6, kk = lin & 63;
            *(bf16x8*)&As[row][kk] = *(const bf16x8*)(Az + (size_t)(bm + row) * K + k0 + kk);
        }
#pragma unroll
        for (int c = 0; c < 2; c++) {
            const int lin = t * 16 + c * 8;
            const int kk = lin >> 6, n0 = lin & 63;
            float v[8];
            ldx8(W, (size_t)(k0 + kk) * N + bn + n0, isb, v);
            const int st = t & 7;
#pragma unroll
            for (int i = 0; i < 8; i++) {
                const int ii = (i + st) & 7;
                Bs[n0 + ii][kk] = f2b(v[ii]);
            }
        }
        __syncthreads();
#pragma unroll
        for (int kc = 0; kc < 2; kc++) {
            bf16x8 af[2], bfr[2];
#pragma unroll
            for (int mi = 0; mi < 2; mi++)
                af[mi] = *(const bf16x8*)&As[wm + mi * 16 + li][kc * 32 + quad * 8];
#pragma unroll
            for (int ni = 0; ni < 2; ni++)
                bfr[ni] = *(const bf16x8*)&Bs[wn + ni * 16 + li][kc * 32 + quad * 8];
#pragma unroll
            for (int mi = 0; mi < 2; mi++)
#pragma unroll
                for (int ni = 0; ni < 2; ni++)
                    acc[mi][ni] = __builtin_amdgcn_mfma_f32_16x16x32_bf16(
                        af[mi], bfr[ni], acc[mi][ni], 0, 0, 0);
        }
        __syncthreads();
    }

    if (mode == 1) {
        bf16* kb = z ? kb1 : kb0;
#pragma unroll
        for (int mi = 0; mi < 2; mi++)
#pragma unroll
            for (int r = 0; r < 4; r++) {
                const int row = bm + wm + mi * 16 + quad * 4 + r;
#pragma unroll
                for (int ni = 0; ni < 2; ni++) {
                    const int col = bn + wn + ni * 16 + li;
                    const float v = acc[mi][ni][r];
                    if (col < 1024)
                        kb[(size_t)row * 1024 + col] = f2b(v);
                    else
                        kb[(size_t)1024 * R + (size_t)(col - 1024) * R + row] = f2b(v);
                }
            }
        return;
    }

#pragma unroll
    for (int mi = 0; mi < 2; mi++)
#pragma unroll
        for (int r = 0; r < 4; r++) {
            const int row = bm + wm + mi * 16 + quad * 4 + r;
#pragma unroll
            for (int ni = 0; ni < 2; ni++) {
                const int col = bn + wn + ni * 16 + li;
                float v = acc[mi][ni][r];
                if (bias) v += ldx(bias, col, isb);
                if (res)  v += ldx(res, roz + (size_t)row * N + col, resb);
                stx(C, coz + (size_t)row * N + col, cb, v);
            }
        }
}

// ---------------------------------------------------------------------------
// attn_flash: round-0 verified 1-wave body. Used by the fallback path.
// ---------------------------------------------------------------------------
__global__ __launch_bounds__(64) void attn_flash(
    const bf16* __restrict__ qb, const bf16* __restrict__ kv0,
    const bf16* __restrict__ kv1,
    const void* __restrict__ rel_emb, bf16* __restrict__ out,
    long qo_bs, long out_bs, int m, int rel_off, const int* __restrict__ flagp) {

    const float SC = 0.125f * 1.44269504f;
    const bool isb = (*flagp != 0);
    const int id = blockIdx.x;
    const int xcd = id & 7;
    const int slot = id >> 3;
    const int c = (slot >> 6) * 8 + xcd;
    const int h = c & 15, z = c >> 4;
    const int q0 = (slot & 63) * 32;
    const int t = threadIdx.x;
    const int li = t & 15, quad = t >> 4;

    const bf16* qz = qb + (size_t)z * qo_bs;
    bf16* oz = out + (size_t)z * out_bs;
    const bf16* kb = z ? kv1 : kv0;
    const bf16* vtb = kb + (size_t)m * 1024;

    __shared__ float bias_s[32];
    __shared__ float tab[2080];
    __shared__ bf16 Ps[16][40];

    if (t < 32) bias_s[t] = ldx(rel_emb, t * 16 + h, isb) * SC - 40.0f;
    __syncthreads();

    const int tsz = m + 31;
    for (int i = t; i < tsz; i += 64) {
        const int rel = i - 31 - q0 + rel_off;
        const int ab = rel < 0 ? -rel : rel;
        int bucket = rel >= 0 ? 16 : 0;
        if (ab < 8) {
            bucket += ab;
        } else {
            const int p = 31 - __clz(ab);
            const int k2 = 2 * p + ((ab * ab >= (1 << (2 * p + 1))) ? 1 : 0);
            const int val = k2 + 2;
            bucket += (val > 15) ? 15 : val;
        }
        tab[i] = bias_s[bucket];
    }
    __syncthreads();

    bf16x8 aq[2][2];
#pragma unroll
    for (int g = 0; g < 2; g++)
#pragma unroll
        for (int kc = 0; kc < 2; kc++)
            aq[g][kc] = *(const bf16x8*)(qz + (size_t)(q0 + g * 16 + li) * 1024
                                         + h * 64 + kc * 32 + quad * 8);

    bf16x8 ones;
#pragma unroll
    for (int j = 0; j < 8; j++) ((short*)&ones)[j] = 0x3F80;

    f32x4 o[2][4], lac[2];
#pragma unroll
    for (int g = 0; g < 2; g++) {
#pragma unroll
        for (int r = 0; r < 4; r++) lac[g][r] = 0.f;
#pragma unroll
        for (int nb = 0; nb < 4; nb++)
#pragma unroll
            for (int r = 0; r < 4; r++) o[g][nb][r] = 0.f;
    }

    for (int j0 = 0; j0 < m; j0 += 32) {
        bf16x8 kf[4], vf[4];
#pragma unroll
        for (int nb = 0; nb < 2; nb++)
#pragma unroll
            for (int kc = 0; kc < 2; kc++)
                kf[nb * 2 + kc] = *(const bf16x8*)(
                    kb + (size_t)(j0 + nb * 16 + li) * 1024 + h * 64 + kc * 32 + quad * 8);
#pragma unroll
        for (int nb = 0; nb < 4; nb++)
            vf[nb] = *(const bf16x8*)(
                vtb + (size_t)(h * 64 + nb * 16 + li) * m + j0 + quad * 8);

#pragma unroll
        for (int g = 0; g < 2; g++) {
            f32x4 s[2];
            __builtin_amdgcn_s_setprio(1);
#pragma unroll
            for (int nb = 0; nb < 2; nb++) {
                f32x4 a;
#pragma unroll
                for (int r = 0; r < 4; r++) a[r] = 0.f;
#pragma unroll
                for (int kc = 0; kc < 2; kc++)
                    a = __builtin_amdgcn_mfma_f32_16x16x32_bf16(aq[g][kc], kf[nb * 2 + kc],
                                                                a, 0, 0, 0);
                s[nb] = a;
            }
            __builtin_amdgcn_s_setprio(0);
#pragma unroll
            for (int nb = 0; nb < 2; nb++)
#pragma unroll
                for (int r = 0; r < 4; r++) {
                    const int ti = j0 + nb * 16 + li + 31 - (g * 16 + quad * 4 + r);
                    s[nb][r] = exp2f(fmaf(s[nb][r], SC, tab[ti]));
                }
#pragma unroll
            for (int nb = 0; nb < 2; nb++)
#pragma unroll
                for (int r = 0; r < 4; r++)
                    Ps[quad * 4 + r][nb * 16 + li] = f2b(s[nb][r]);
            const bf16x8 ap = *(const bf16x8*)&Ps[li][quad * 8];
            __builtin_amdgcn_s_setprio(1);
#pragma unroll
            for (int nb = 0; nb < 4; nb++)
                o[g][nb] = __builtin_amdgcn_mfma_f32_16x16x32_bf16(ap, vf[nb],
                                                                   o[g][nb], 0, 0, 0);
            lac[g] = __builtin_amdgcn_mfma_f32_16x16x32_bf16(ap, ones, lac[g], 0, 0, 0);
            __builtin_amdgcn_s_setprio(0);
        }
    }

#pragma unroll
    for (int g = 0; g < 2; g++)
#pragma unroll
        for (int r = 0; r < 4; r++) {
            const float inv = 1.0f / lac[g][r];
            const int qi = q0 + g * 16 + quad * 4 + r;
#pragma unroll
            for (int nb = 0; nb < 4; nb++)
                oz[(size_t)qi * 1024 + h * 64 + nb * 16 + li] = f2b(o[g][nb][r] * inv);
        }
}

// ---------------------------------------------------------------------------
// ROUND 16 (retry; round-16 bench was an infra failure): attn_flash64 —
// 64 queries per wave (g-loop of 4), 4 independent waves/block, zero
// barriers. Round-15 resolved the regime: occupancy rose to 36% yet time
// DOUBLED with doubled load-instruction count -> the kernel is K/V
// LOAD-THROUGHPUT-bound (t ~ 25 µs + 0.054 µs/wave from the 2048/4096-wave
// fit). This lever HALVES total loads: 1024 waves, loads per K-tile
// unchanged (8) but reused across 4 q-groups. Predicted SA ~80-100 µs.
// VGPR ~200 (1 wave/SIMD — latency hiding measured to contribute little in
// this regime). Falsification: SA >= 136.5 -> revert to round-14, converge.
// ---------------------------------------------------------------------------
__global__ __launch_bounds__(256) void attn_flash64(
    const bf16* __restrict__ qb, const bf16* __restrict__ kv0,
    const bf16* __restrict__ kv1,
    const void* __restrict__ rel_emb, bf16* __restrict__ out,
    long qo_bs, long out_bs, int m, int rel_off, const int* __restrict__ flagp) {

    const float SC = 0.125f * 1.44269504f;
    const bool isb = (*flagp != 0);
    const int t256 = threadIdx.x;
    const int w = t256 >> 6;                  // wave id 0..3
    const int t = t256 & 63;                  // lane
    const int id = (int)blockIdx.x * 4 + w;   // 0..1023
    const int xcd = id & 7;
    const int slot = id >> 3;                 // 0..127
    const int c = (slot >> 5) * 8 + xcd;      // 0..31
    const int h = c & 15, z = c >> 4;
    const int q0 = (slot & 31) * 64;          // 64-query tiles
    const int li = t & 15, quad = t >> 4;

    const bf16* qz = qb + (size_t)z * qo_bs;
    bf16* oz = out + (size_t)z * out_bs;
    const bf16* kb = z ? kv1 : kv0;
    const bf16* vtb = kb + (size_t)m * 1024;

    // Per-wave private LDS slices (no block barriers anywhere).
    __shared__ float tabS[4][2112];           // covers m+63 <= 2111
    __shared__ float biasS[4][32];
    __shared__ bf16  PsS[4][16][40];
    float* tab = tabS[w];
    float* bias_s = biasS[w];
    bf16 (*Ps)[40] = PsS[w];

    if (t < 32) bias_s[t] = ldx(rel_emb, t * 16 + h, isb) * SC - 40.0f;
    // wave-internal LDS RAW: compiler-inserted lgkmcnt (verified Ps pattern)

    const int tsz = m + 63;
    for (int i = t; i < tsz; i += 64) {
        const int rel = i - 63 - q0 + rel_off;
        const int ab = rel < 0 ? -rel : rel;
        int bucket = rel >= 0 ? 16 : 0;
        if (ab < 8) {
            bucket += ab;
        } else {
            const int p = 31 - __clz(ab);
            const int k2 = 2 * p + ((ab * ab >= (1 << (2 * p + 1))) ? 1 : 0);
            const int val = k2 + 2;
            bucket += (val > 15) ? 15 : val;
        }
        tab[i] = bias_s[bucket];
    }

    bf16x8 aq[4][2];
#pragma unroll
    for (int g = 0; g < 4; g++)
#pragma unroll
        for (int kc = 0; kc < 2; kc++)
            aq[g][kc] = *(const bf16x8*)(qz + (size_t)(q0 + g * 16 + li) * 1024
                                         + h * 64 + kc * 32 + quad * 8);

    bf16x8 ones;
#pragma unroll
    for (int j = 0; j < 8; j++) ((short*)&ones)[j] = 0x3F80;

    f32x4 o[4][4], lac[4];
#pragma unroll
    for (int g = 0; g < 4; g++) {
#pragma unroll
        for (int r = 0; r < 4; r++) lac[g][r] = 0.f;
#pragma unroll
        for (int nb = 0; nb < 4; nb++)
#pragma unroll
            for (int r = 0; r < 4; r++) o[g][nb][r] = 0.f;
    }

    for (int j0 = 0; j0 < m; j0 += 32) {
        bf16x8 kf[4], vf[4];
#pragma unroll
        for (int nb = 0; nb < 2; nb++)
#pragma unroll
            for (int kc = 0; kc < 2; kc++)
                kf[nb * 2 + kc] = *(const bf16x8*)(
                    kb + (size_t)(j0 + nb * 16 + li) * 1024 + h * 64 + kc * 32 + quad * 8);
#pragma unroll
        for (int nb = 0; nb < 4; nb++)
            vf[nb] = *(const bf16x8*)(
                vtb + (size_t)(h * 64 + nb * 16 + li) * m + j0 + quad * 8);

#pragma unroll
        for (int g = 0; g < 4; g++) {
            f32x4 s[2];
            __builtin_amdgcn_s_setprio(1);
#pragma unroll
            for (int nb = 0; nb < 2; nb++) {
                f32x4 a;
#pragma unroll
                for (int r = 0; r < 4; r++) a[r] = 0.f;
#pragma unroll
                for (int kc = 0; kc < 2; kc++)
                    a = __builtin_amdgcn_mfma_f32_16x16x32_bf16(aq[g][kc], kf[nb * 2 + kc],
                                                                a, 0, 0, 0);
                s[nb] = a;
            }
            __builtin_amdgcn_s_setprio(0);
#pragma unroll
            for (int nb = 0; nb < 2; nb++)
#pragma unroll
                for (int r = 0; r < 4; r++) {
                    const int ti = j0 + nb * 16 + li + 63 - (g * 16 + quad * 4 + r);
                    s[nb][r] = exp2f(fmaf(s[nb][r], SC, tab[ti]));
                }
#pragma unroll
            for (int nb = 0; nb < 2; nb++)
#pragma unroll
                for (int r = 0; r < 4; r++)
                    Ps[quad * 4 + r][nb * 16 + li] = f2b(s[nb][r]);
            const bf16x8 ap = *(const bf16x8*)&Ps[li][quad * 8];
            __builtin_amdgcn_s_setprio(1);
#pragma unroll
            for (int nb = 0; nb < 4; nb++)
                o[g][nb] = __builtin_amdgcn_mfma_f32_16x16x32_bf16(ap, vf[nb],
                                                                   o[g][nb], 0, 0, 0);
            lac[g] = __builtin_amdgcn_mfma_f32_16x16x32_bf16(ap, ones, lac[g], 0, 0, 0);
            __builtin_amdgcn_s_setprio(0);
        }
    }

#pragma unroll
    for (int g = 0; g < 4; g++)
#pragma unroll
        for (int r = 0; r < 4; r++) {
            const float inv = 1.0f / lac[g][r];
            const int qi = q0 + g * 16 + quad * 4 + r;
#pragma unroll
            for (int nb = 0; nb < 4; nb++)
                oz[(size_t)qi * 1024 + h * 64 + nb * 16 + li] = f2b(o[g][nb][r] * inv);
        }
}

// ---------------------------------------------------------------------------
// Launcher. Fast path (ws >= 56 MB + 256; measured ws = 256 MB):
//   F_A|F_B|F_C (24 MB) + WT (8) + F_X (8) + F_Y (6) + WT2 (8) = 54 MB.
// Round-14 schedule (best: 448.0 µs) with attn on attn_flash64 (64 q/wave,
// 1024 waves -> HALVED load instructions). Fallback: round-7 plan (24 MB).
// ---------------------------------------------------------------------------
extern "C" void kernel_launch(void* const* d_in, const int* in_sizes, int n_in,
                              void* d_out, int out_size, void* d_ws, size_t ws_size,
                              hipStream_t stream) {
    const long M1 = 1024 * 1024;
    const long M2 = 2 * 1024 * 1024;
    const long M4 = 4 * 1024 * 1024;
    if (ws_size < 24u * 1024 * 1024 + 256) return;

    const void* x      = d_in[0];
    const void* ctx    = d_in[1];
    const void* sa_ng  = d_in[2];
    const void* sa_nb  = d_in[3];
    const void* sa_ncg = d_in[4];
    const void* sa_ncb = d_in[5];
    const void* sa_wq  = d_in[6];
    const void* sa_wkv = d_in[7];
    const void* sa_wo  = d_in[8];
    const void* sa_bo  = d_in[9];
    const void* sa_rel = d_in[10];
    const void* ca_ng  = d_in[11];
    const void* ca_nb  = d_in[12];
    const void* ca_ncg = d_in[13];
    const void* ca_ncb = d_in[14];
    const void* ca_wq  = d_in[15];
    const void* ca_wkv = d_in[16];
    const void* ca_wo  = d_in[17];
    const void* ca_bo  = d_in[18];
    const void* ca_rel = d_in[19];

    int* flag = (int*)d_ws;
    bf16* F_A = (bf16*)((char*)d_ws + 256);
    bf16* F_B = F_A + M4;
    bf16* F_C = F_B + M4;
    bf16* WT  = F_C + M4;                // fast path only (SA weights)
    bf16* F_X = WT + M4;                 // fast path only (xn buffer)
    bf16* F_Y = F_X + M4;                // fast path only (ctx-LN + CA K/V)
    bf16* WT2 = F_Y + 3 * M1;            // fast path only (CA weights)
    bf16* qd  = (bf16*)d_out;            // d_out as bf16 scratch (q / ao)

    sniff_kernel<<<1, 256, 0, stream>>>(x, flag);

    if (ws_size >= 56u * 1024 * 1024 + 256) {
        bf16* WTq  = WT;                 // [1024][1024]
        bf16* WTkv = WT + M1;            // [2048][1024]
        bf16* WTo  = WT + 3 * M1;        // [1024][1024]
        bf16* WT2q  = WT2;
        bf16* WT2kv = WT2 + M1;
        bf16* WT2o  = WT2 + 3 * M1;
        bf16* CAK0 = F_Y + M1;           // z0: K[512][1024] + V^T[1024][512]
        bf16* CAK1 = F_Y + 2 * M1;       // z1: same layout

        // ===== prologue: weight transposes + both input LNs (ONE dispatch)
        prologue_kernel<<<dim3(7168), 256, 0, stream>>>(
            sa_wq, sa_wkv, sa_wo, ca_wq, ca_wkv, ca_wo,
            WTq, WTkv, WTo, WT2q, WT2kv, WT2o,
            x, ctx, sa_ng, sa_nb, sa_ncg, sa_ncb, ca_ncg, ca_ncb,
            F_X, F_B, F_Y, flag);

        // ===== BIG (128^2): SA-q + SA-kv + CA-kv =====
        {
            GArgs gq = {};
            gq.A = F_X; gq.Bt = WTq; gq.C = qd;
            gq.N = 1024; gq.nbx = 8; gq.nby = 32;
            GArgs gkv = {};
            gkv.A = F_B; gkv.Bt = WTkv;
            gkv.N = 2048; gkv.mode = 1; gkv.zsplit = 2048; gkv.zrows = 2048;
            gkv.kb0 = F_A; gkv.kb1 = F_C; gkv.nbx = 16; gkv.nby = 32;
            GArgs gca = {};
            gca.A = F_Y; gca.Bt = WT2kv;
            gca.N = 2048; gca.mode = 1; gca.zsplit = 512; gca.zrows = 512;
            gca.kb0 = CAK0; gca.kb1 = CAK1; gca.nbx = 16; gca.nby = 8;
            gemm_fused<<<dim3(40, 32), 256, 0, stream>>>(gq, gkv, gca, flag);
        }

        // ===== self-attention + o-proj =====
        attn_flash64<<<dim3(256), 256, 0, stream>>>(
            qd, F_A, F_C, sa_rel, qd, M2, M2, 2048, 0, flag);
        gemm_t64<<<dim3(16, 64), 256, 0, stream>>>(
            qd, WTo, F_B, 0, sa_bo, x, 1, 1024, flag);

        // ===== cross-attention =====
        ln_dual_kernel<<<dim3(2048, 1, 2), 256, 0, stream>>>(
            F_B, 0, M2, 0, ca_ng, ca_nb, nullptr, nullptr, F_X, nullptr, M2, flag);
        gemm_t64<<<dim3(16, 64), 256, 0, stream>>>(
            F_X, WT2q, qd, 0, nullptr, nullptr, 0, 1024, flag);
        attn_flash64<<<dim3(256), 256, 0, stream>>>(
            qd, CAK0, CAK1, ca_rel, F_C, M2, M2, 512, 1536, flag);
        gemm_t64<<<dim3(16, 64), 256, 0, stream>>>(
            F_C, WT2o, d_out, 1, ca_bo, F_B, 0, 1024, flag);
        return;
    }

    // ================= fallback: round-7 verified plan =================
    ln_dual_kernel<<<dim3(2048, 1, 2), 256, 0, stream>>>(
        x, 0, M2, 1, sa_ng, sa_nb, sa_ncg, sa_ncb, F_A, F_B, M2, flag);
    gemm_mfma<<<dim3(16, 32, 2), 256, 0, stream>>>(
        F_A, M2, sa_wq, qd, 0, M2, 0, nullptr, nullptr, 0, 0, 0,
        1024, 1024, 0, 0, nullptr, nullptr, flag);
    gemm_mfma<<<dim3(32, 32, 2), 256, 0, stream>>>(
        F_B, M2, sa_wkv, nullptr, 0, 0, 0, nullptr, nullptr, 0, 0, 0,
        1024, 2048, 1, 2048, F_A, F_C, flag);
    attn_flash<<<dim3(2048), 64, 0, stream>>>(
        qd, F_A, F_C, sa_rel, qd, M2, M2, 2048, 0, flag);
    gemm_mfma<<<dim3(16, 32, 2), 256, 0, stream>>>(
        qd, M2, sa_wo, F_B, 0, M2, 0, sa_bo, x, 0, M2, 1,
        1024, 1024, 0, 0, nullptr, nullptr, flag);

    ln_dual_kernel<<<dim3(2048, 1, 2), 256, 0, stream>>>(
        F_B, 0, M2, 0, ca_ng, ca_nb, nullptr, nullptr, F_A, nullptr, M2, flag);
    ln_dual_kernel<<<dim3(512, 1, 2), 256, 0, stream>>>(
        ctx, 0, 512 * 1024, 1, ca_ncg, ca_ncb, nullptr, nullptr,
        F_C, nullptr, 512 * 1024, flag);
    gemm_mfma<<<dim3(16, 32, 2), 256, 0, stream>>>(
        F_A, M2, ca_wq, qd, 0, M2, 0, nullptr, nullptr, 0, 0, 0,
        1024, 1024, 0, 0, nullptr, nullptr, flag);
    gemm_mfma<<<dim3(32, 8, 2), 256, 0, stream>>>(
        F_C, 512 * 1024, ca_wkv, nullptr, 0, 0, 0, nullptr, nullptr, 0, 0, 0,
        1024, 2048, 1, 512, F_A, F_A + M1, flag);
    attn_flash<<<dim3(2048), 64, 0, stream>>>(
        qd, F_A, F_A + M1, ca_rel, F_C, M2, M2, 512, 1536, flag);
    gemm_mfma<<<dim3(16, 32, 2), 256, 0, stream>>>(
        F_C, M2, ca_wo, d_out, 0, M2, 1, ca_bo, F_B, 0, M2, 0,
        1024, 1024, 0, 0, nullptr, nullptr, flag);
}

// Round 18
// 421.671 us; speedup vs baseline: 1.3843x; 1.0450x over previous
//
#include <hip/hip_runtime.h>
#include <hip/hip_bf16.h>

typedef __hip_bfloat16 bf16;
typedef __attribute__((ext_vector_type(8))) short bf16x8;   // 8 bf16 (4 VGPRs)
typedef __attribute__((ext_vector_type(4))) float f32x4;    // MFMA accum

__device__ __forceinline__ float b2f(bf16 v) { return __bfloat162float(v); }
__device__ __forceinline__ bf16 f2b(float v) { return __float2bfloat16(v); }

// Scalar load/store from an external buffer whose dtype is decided by isb.
__device__ __forceinline__ float ldx(const void* p, size_t i, bool isb) {
    return isb ? b2f(((const bf16*)p)[i]) : ((const float*)p)[i];
}
__device__ __forceinline__ void stx(void* p, size_t i, bool isb, float v) {
    if (isb) ((bf16*)p)[i] = f2b(v);
    else     ((float*)p)[i] = v;
}
// Vector (8-elem) external load; i must be a multiple of 8.
__device__ __forceinline__ void ldx8(const void* p, size_t i, bool isb, float* o) {
    if (isb) {
        const bf16x8 v = *(const bf16x8*)((const bf16*)p + i);
#pragma unroll
        for (int j = 0; j < 8; j++) o[j] = b2f(((const bf16*)&v)[j]);
    } else {
        const float4 v0 = *(const float4*)((const float*)p + i);
        const float4 v1 = *(const float4*)((const float*)p + i + 4);
        o[0]=v0.x; o[1]=v0.y; o[2]=v0.z; o[3]=v0.w;
        o[4]=v1.x; o[5]=v1.y; o[6]=v1.z; o[7]=v1.w;
    }
}

// ---------------------------------------------------------------------------
// Dtype sniffer (verified round 3): decides fp32 vs bf16 external data.
// ---------------------------------------------------------------------------
__global__ void sniff_kernel(const void* __restrict__ x, int* __restrict__ flag) {
    const unsigned* w = (const unsigned*)x;
    const int t = threadIdx.x;
    int cnt = 0;
#pragma unroll
    for (int i = 0; i < 4; i++) {
        const unsigned word = w[t * 4 + i];
        const int e = (word >> 23) & 0xFF;
        cnt += (e >= 192) ? 1 : 0;
    }
    __shared__ int red[4];
#pragma unroll
    for (int o = 32; o > 0; o >>= 1) cnt += __shfl_down(cnt, o);
    if ((t & 63) == 0) red[t >> 6] = cnt;
    __syncthreads();
    if (t == 0) flag[0] = ((red[0] + red[1] + red[2] + red[3]) >= 512) ? 1 : 0;
}

// ---------------------------------------------------------------------------
// Merged PROLOGUE kernel (round-13 verified WIN): weight transposes (both
// phases) AND both input LNs in ONE dispatch. Block-uniform demux.
// ---------------------------------------------------------------------------
__global__ void prologue_kernel(
    const void* __restrict__ Wq,  const void* __restrict__ Wkv,
    const void* __restrict__ Wo,  const void* __restrict__ Wq2,
    const void* __restrict__ Wkv2, const void* __restrict__ Wo2,
    bf16* __restrict__ WTq,  bf16* __restrict__ WTkv,  bf16* __restrict__ WTo,
    bf16* __restrict__ WTq2, bf16* __restrict__ WTkv2, bf16* __restrict__ WTo2,
    const void* __restrict__ x, const void* __restrict__ ctx,
    const void* __restrict__ g1, const void* __restrict__ b1,
    const void* __restrict__ g2, const void* __restrict__ b2,
    const void* __restrict__ g3, const void* __restrict__ b3,
    bf16* __restrict__ outX, bf16* __restrict__ outB, bf16* __restrict__ outY,
    const int* __restrict__ flagp) {

    const bool isb = (*flagp != 0);
    const int bid = blockIdx.x;
    const int t = threadIdx.x;

    __shared__ __align__(16) char smem[16640];   // 64*65*4 = 16640 B

    if (bid < 2048) {
        // ================= wconv path (verified wconv8 body) =============
        float (*T)[65] = (float(*)[65])smem;
        const int bx = bid & 15, by = (bid >> 4) & 15, z = bid >> 8;
        const int zz = z & 3;
        const bool ca = z >= 4;
        const void* W = ca ? ((zz == 0) ? Wq2 : (zz == 3) ? Wo2 : Wkv2)
                           : ((zz == 0) ? Wq  : (zz == 3) ? Wo  : Wkv);
        bf16* Wt      = ca ? ((zz == 0) ? WTq2 : (zz == 3) ? WTo2 : WTkv2)
                           : ((zz == 0) ? WTq  : (zz == 3) ? WTo  : WTkv);
        const int N   = (zz == 1 || zz == 2) ? 2048 : 1024;
        const int K = 1024;
        const int n0 = bx * 64 + ((zz == 2) ? 1024 : 0);
        const int k0 = by * 64;
        const int rr = t >> 3, c8 = (t & 7) * 8;
#pragma unroll
        for (int i = 0; i < 2; i++) {
            const int row = rr + i * 32;
            float v[8];
            ldx8(W, (size_t)(k0 + row) * N + n0 + c8, isb, v);
#pragma unroll
            for (int j = 0; j < 8; j++) T[row][c8 + j] = v[j];
        }
        __syncthreads();
#pragma unroll
        for (int i = 0; i < 2; i++) {
            const int row = rr + i * 32;   // n-index within tile
            bf16x8 ov;
#pragma unroll
            for (int j = 0; j < 8; j++) ((bf16*)&ov)[j] = f2b(T[c8 + j][row]);
            *(bf16x8*)(Wt + (size_t)(n0 + row) * K + k0 + c8) = ov;
        }
        return;
    }

    // =================== LN path (verified ln_pro body) ==================
    const int F = 1024;
    float* red1 = (float*)smem;
    float* red2 = (float*)smem + 4;
    const int lnid = bid - 2048;             // 0..5119
    const int z = (lnid >= 2560) ? 1 : 0;
    const int bid2 = lnid - z * 2560;        // 0..2559
    const bool isCtx = bid2 >= 2048;
    const int row = isCtx ? bid2 - 2048 : bid2;
    const void* in = isCtx ? ctx : x;
    const size_t base = (isCtx ? (size_t)z * (512 * 1024)
                               : (size_t)z * (2048 * 1024)) + (size_t)row * F;

    float v[4];
    float s = 0.f;
#pragma unroll
    for (int i = 0; i < 4; i++) { v[i] = ldx(in, base + t + 256 * i, isb); s += v[i]; }

#pragma unroll
    for (int o = 32; o > 0; o >>= 1) s += __shfl_down(s, o);
    if ((t & 63) == 0) red1[t >> 6] = s;
    __syncthreads();
    const float mean = (red1[0] + red1[1] + red1[2] + red1[3]) * (1.0f / F);

    float ss = 0.f;
#pragma unroll
    for (int i = 0; i < 4; i++) { float d = v[i] - mean; ss += d * d; }
#pragma unroll
    for (int o = 32; o > 0; o >>= 1) ss += __shfl_down(ss, o);
    if ((t & 63) == 0) red2[t >> 6] = ss;
    __syncthreads();
    const float var = (red2[0] + red2[1] + red2[2] + red2[3]) * (1.0f / F);
    const float rn = rsqrtf(var + 1e-5f);

    if (isCtx) {
        const size_t obase = (size_t)z * (512 * 1024) + (size_t)row * F;
#pragma unroll
        for (int i = 0; i < 4; i++) {
            const int idx = t + 256 * i;
            const float nv = (v[i] - mean) * rn;
            outY[obase + idx] = f2b(nv * ldx(g3, idx, isb) + ldx(b3, idx, isb));
        }
    } else {
        const size_t obase = (size_t)z * (2048 * 1024) + (size_t)row * F;
#pragma unroll
        for (int i = 0; i < 4; i++) {
            const int idx = t + 256 * i;
            const float nv = (v[i] - mean) * rn;
            outX[obase + idx] = f2b(nv * ldx(g1, idx, isb) + ldx(b1, idx, isb));
            outB[obase + idx] = f2b(nv * ldx(g2, idx, isb) + ldx(b2, idx, isb));
        }
    }
}

// ---------------------------------------------------------------------------
// LayerNorm over F=1024, batch-fused via grid.z (per-batch strides in elems).
// Used for the mid-pipeline CA-x LN (and the fallback path).
// ---------------------------------------------------------------------------
__global__ void ln_dual_kernel(const void* __restrict__ in, size_t in_off, long in_bs,
                               int in_ext,
                               const void* __restrict__ g1, const void* __restrict__ b1,
                               const void* __restrict__ g2, const void* __restrict__ b2,
                               bf16* __restrict__ out1, bf16* __restrict__ out2,
                               long out_bs, const int* __restrict__ flagp) {
    const int F = 1024;
    const bool isb = (*flagp != 0);
    const bool inb = in_ext ? isb : true;
    const int row = blockIdx.x;
    const int z = blockIdx.z;
    const int t = threadIdx.x;
    const size_t base = in_off + (size_t)z * in_bs + (size_t)row * F;
    const size_t obase = (size_t)z * out_bs + (size_t)row * F;

    float v[4];
    float s = 0.f;
#pragma unroll
    for (int i = 0; i < 4; i++) { v[i] = ldx(in, base + t + 256 * i, inb); s += v[i]; }

    __shared__ float red1[4];
    __shared__ float red2[4];
#pragma unroll
    for (int o = 32; o > 0; o >>= 1) s += __shfl_down(s, o);
    if ((t & 63) == 0) red1[t >> 6] = s;
    __syncthreads();
    const float mean = (red1[0] + red1[1] + red1[2] + red1[3]) * (1.0f / F);

    float ss = 0.f;
#pragma unroll
    for (int i = 0; i < 4; i++) { float d = v[i] - mean; ss += d * d; }
#pragma unroll
    for (int o = 32; o > 0; o >>= 1) ss += __shfl_down(ss, o);
    if ((t & 63) == 0) red2[t >> 6] = ss;
    __syncthreads();
    const float var = (red2[0] + red2[1] + red2[2] + red2[3]) * (1.0f / F);
    const float rn = rsqrtf(var + 1e-5f);

#pragma unroll
    for (int i = 0; i < 4; i++) {
        const int idx = t + 256 * i;
        const float nv = (v[i] - mean) * rn;
        out1[obase + idx] = f2b(nv * ldx(g1, idx, isb) + ldx(b1, idx, isb));
        if (out2) out2[obase + idx] = f2b(nv * ldx(g2, idx, isb) + ldx(b2, idx, isb));
    }
}

// ---------------------------------------------------------------------------
// Grouped GEMM args. C = A[R,1024] @ Bt^T, 128x128 tile, BK=64, 4 waves.
// ---------------------------------------------------------------------------
struct GArgs {
    const bf16* A; const bf16* Bt; void* C;
    const void* bias; const void* res;
    bf16* kb0; bf16* kb1;
    int c_ext, res_ext, N, mode, zsplit, zrows, nbx, nby;
};

// ---------------------------------------------------------------------------
// Reg-staged grouped GEMM (verified body, padded LDS). Mode-1 V-half writes
// V^T via LDS transpose (round-8 win). Used for the BIG 3-slot dispatch at
// 128^2 tiles / 3.5 blocks/CU — round 11 proved 64^2 tiles REGRESS here.
// ---------------------------------------------------------------------------
__global__ __launch_bounds__(256) void gemm_fused(GArgs ga, GArgs gb, GArgs gc,
                                                  const int* __restrict__ flagp) {
    int bx = (int)blockIdx.x;
    GArgs g;
    if (bx < ga.nbx) { g = ga; }
    else if (bx < ga.nbx + gb.nbx) { g = gb; bx -= ga.nbx; }
    else { g = gc; bx -= ga.nbx + gb.nbx; }
    const int by = (int)blockIdx.y;
    if (by >= g.nby) return;               // block-uniform: no divergent barrier

    const int K = 1024;
    const bool isb = (*flagp != 0);

    __shared__ bf16 As[128][72];
    __shared__ bf16 Bs[128][72];

    const int t = threadIdx.x;
    const int w = t >> 6, lane = t & 63, li = lane & 15, quad = lane >> 4;
    const int wm = (w & 1) * 64, wn = (w >> 1) * 64;
    const int bm = by * 128, bn = bx * 128;

    f32x4 acc[4][4];
#pragma unroll
    for (int mi = 0; mi < 4; mi++)
#pragma unroll
        for (int ni = 0; ni < 4; ni++)
#pragma unroll
            for (int r = 0; r < 4; r++) acc[mi][ni][r] = 0.f;

    for (int k0 = 0; k0 < K; k0 += 64) {
#pragma unroll
        for (int c = 0; c < 4; c++) {
            const int d = c * 256 + t;
            const int row = d >> 3, ch = (d & 7) * 8;
            *(bf16x8*)&As[row][ch] = *(const bf16x8*)(g.A + (size_t)(bm + row) * K + k0 + ch);
            *(bf16x8*)&Bs[row][ch] = *(const bf16x8*)(g.Bt + (size_t)(bn + row) * K + k0 + ch);
        }
        __syncthreads();
#pragma unroll
        for (int kc = 0; kc < 2; kc++) {
            bf16x8 af[4], bfr[4];
#pragma unroll
            for (int i = 0; i < 4; i++) {
                af[i]  = *(const bf16x8*)&As[wm + i * 16 + li][kc * 32 + quad * 8];
                bfr[i] = *(const bf16x8*)&Bs[wn + i * 16 + li][kc * 32 + quad * 8];
            }
#pragma unroll
            for (int mi = 0; mi < 4; mi++)
#pragma unroll
                for (int ni = 0; ni < 4; ni++)
                    acc[mi][ni] = __builtin_amdgcn_mfma_f32_16x16x32_bf16(
                        af[mi], bfr[ni], acc[mi][ni], 0, 0, 0);
        }
        __syncthreads();
    }

    if (g.mode == 1) {
        if (bn >= 1024) {
            // -------- V block: LDS-transposed coalesced V^T store --------
            const int batch = (bm < g.zsplit) ? 0 : 1;
            bf16* kb = batch ? g.kb1 : g.kb0;
            const int brow = bm - batch * g.zsplit;
            const int vc0 = bn - 1024;
            bf16 (*T)[136] = (bf16(*)[136])&As[0][0];   // 64x136 fits in As
            const int c = t >> 2, seg = t & 3;           // c: V^T row, seg: 64B
#pragma unroll
            for (int p = 0; p < 2; p++) {
                if ((w >> 1) == p) {                     // waves owning cols p*64..
#pragma unroll
                    for (int mi = 0; mi < 4; mi++)
#pragma unroll
                        for (int ni = 0; ni < 4; ni++)
#pragma unroll
                            for (int r = 0; r < 4; r++)
                                T[ni * 16 + li][wm + mi * 16 + quad * 4 + r] =
                                    f2b(acc[mi][ni][r]);
                }
                __syncthreads();
                bf16* dst = kb + (size_t)1024 * g.zrows
                            + (size_t)(vc0 + p * 64 + c) * g.zrows + brow + seg * 32;
#pragma unroll
                for (int j = 0; j < 4; j++)
                    *(bf16x8*)(dst + j * 8) = *(const bf16x8*)&T[c][seg * 32 + j * 8];
                __syncthreads();
            }
            return;
        }
        // -------- K block: verified coalesced row-major store --------
#pragma unroll
        for (int mi = 0; mi < 4; mi++)
#pragma unroll
            for (int r = 0; r < 4; r++) {
                const int row = bm + wm + mi * 16 + quad * 4 + r;
                bf16* kb = (row < g.zsplit) ? g.kb0 : g.kb1;
                const int lrow = (row < g.zsplit) ? row : row - g.zsplit;
#pragma unroll
                for (int ni = 0; ni < 4; ni++) {
                    const int col = bn + wn + ni * 16 + li;
                    kb[(size_t)lrow * 1024 + col] = f2b(acc[mi][ni][r]);
                }
            }
        return;
    }

#pragma unroll
    for (int mi = 0; mi < 4; mi++)
#pragma unroll
        for (int r = 0; r < 4; r++) {
            const int row = bm + wm + mi * 16 + quad * 4 + r;
#pragma unroll
            for (int ni = 0; ni < 4; ni++) {
                const int col = bn + wn + ni * 16 + li;
                float v = acc[mi][ni][r];
                if (g.bias) v += ldx(g.bias, col, isb);
                if (g.res)  v += ldx(g.res, (size_t)row * g.N + col, g.res_ext ? isb : true);
                stx(g.C, (size_t)row * g.N + col, g.c_ext ? isb : true, v);
            }
        }
}

// ---------------------------------------------------------------------------
// Round-10 verified: 64x64-tile mode-0 GEMM for the three standalone GEMMs
// (SA-oproj, CA-q, CA-oproj), grid (16,64) = 4 blocks/CU. WIN: −21.6 µs.
// ---------------------------------------------------------------------------
__global__ __launch_bounds__(256) void gemm_t64(
    const bf16* __restrict__ A, const bf16* __restrict__ Bt,
    void* __restrict__ C, int c_ext,
    const void* __restrict__ bias,
    const void* __restrict__ res, int res_ext, int N,
    const int* __restrict__ flagp) {

    const int K = 1024;
    const bool isb = (*flagp != 0);

    __shared__ bf16 As[64][72];
    __shared__ bf16 Bs[64][72];

    const int t = threadIdx.x;
    const int w = t >> 6, lane = t & 63, li = lane & 15, quad = lane >> 4;
    const int wm = (w & 1) * 32, wn = (w >> 1) * 32;
    const int bm = blockIdx.y * 64, bn = blockIdx.x * 64;

    f32x4 acc[2][2];
#pragma unroll
    for (int mi = 0; mi < 2; mi++)
#pragma unroll
        for (int ni = 0; ni < 2; ni++)
#pragma unroll
            for (int r = 0; r < 4; r++) acc[mi][ni][r] = 0.f;

    for (int k0 = 0; k0 < K; k0 += 64) {
#pragma unroll
        for (int c = 0; c < 2; c++) {
            const int d = c * 256 + t;
            const int row = d >> 3, ch = (d & 7) * 8;
            *(bf16x8*)&As[row][ch] = *(const bf16x8*)(A + (size_t)(bm + row) * K + k0 + ch);
            *(bf16x8*)&Bs[row][ch] = *(const bf16x8*)(Bt + (size_t)(bn + row) * K + k0 + ch);
        }
        __syncthreads();
#pragma unroll
        for (int kc = 0; kc < 2; kc++) {
            bf16x8 af[2], bfr[2];
#pragma unroll
            for (int mi = 0; mi < 2; mi++)
                af[mi] = *(const bf16x8*)&As[wm + mi * 16 + li][kc * 32 + quad * 8];
#pragma unroll
            for (int ni = 0; ni < 2; ni++)
                bfr[ni] = *(const bf16x8*)&Bs[wn + ni * 16 + li][kc * 32 + quad * 8];
#pragma unroll
            for (int mi = 0; mi < 2; mi++)
#pragma unroll
                for (int ni = 0; ni < 2; ni++)
                    acc[mi][ni] = __builtin_amdgcn_mfma_f32_16x16x32_bf16(
                        af[mi], bfr[ni], acc[mi][ni], 0, 0, 0);
        }
        __syncthreads();
    }

#pragma unroll
    for (int mi = 0; mi < 2; mi++)
#pragma unroll
        for (int r = 0; r < 4; r++) {
            const int row = bm + wm + mi * 16 + quad * 4 + r;
#pragma unroll
            for (int ni = 0; ni < 2; ni++) {
                const int col = bn + wn + ni * 16 + li;
                float v = acc[mi][ni][r];
                if (bias) v += ldx(bias, col, isb);
                if (res)  v += ldx(res, (size_t)row * N + col, res_ext ? isb : true);
                stx(C, (size_t)row * N + col, c_ext ? isb : true, v);
            }
        }
}

// ---------------------------------------------------------------------------
// Slow-path MFMA GEMM (round-7 verified, used only if workspace is small).
// ---------------------------------------------------------------------------
__global__ __launch_bounds__(256) void gemm_mfma(
    const bf16* __restrict__ A, long a_bs, const void* __restrict__ W,
    void* __restrict__ C, size_t c_off, long c_bs, int c_ext,
    const void* __restrict__ bias,
    const void* __restrict__ res, size_t res_off, long res_bs, int res_ext,
    int K, int N, int mode, int R,
    bf16* __restrict__ kb0, bf16* __restrict__ kb1,
    const int* __restrict__ flagp) {

    const bool isb = (*flagp != 0);
    const bool resb = res_ext ? isb : true;
    const bool cb = c_ext ? isb : true;
    const int z = blockIdx.z;

    const bf16* Az = A + (size_t)z * a_bs;
    const size_t coz = c_off + (size_t)z * c_bs;
    const size_t roz = res_off + (size_t)z * res_bs;

    __shared__ bf16 As[64][72];
    __shared__ bf16 Bs[64][72];

    const int t = threadIdx.x;
    const int w = t >> 6, lane = t & 63, li = lane & 15, quad = lane >> 4;
    const int wm = (w & 1) * 32, wn = (w >> 1) * 32;
    const int bm = blockIdx.y * 64, bn = blockIdx.x * 64;

    f32x4 acc[2][2];
#pragma unroll
    for (int mi = 0; mi < 2; mi++)
#pragma unroll
        for (int ni = 0; ni < 2; ni++)
#pragma unroll
            for (int r = 0; r < 4; r++) acc[mi][ni][r] = 0.f;

    for (int k0 = 0; k0 < K; k0 += 64) {
#pragma unroll
        for (int c = 0; c < 2; c++) {
            const int lin = t * 16 + c * 8;
            const int row = lin >> 6, kk = lin & 63;
            *(bf16x8*)&As[row][kk] = *(const bf16x8*)(Az + (size_t)(bm + row) * K + k0 + kk);
        }
#pragma unroll
        for (int c = 0; c < 2; c++) {
            const int lin = t * 16 + c * 8;
            const int kk = lin >> 6, n0 = lin & 63;
            float v[8];
            ldx8(W, (size_t)(k0 + kk) * N + bn + n0, isb, v);
            const int st = t & 7;
#pragma unroll
            for (int i = 0; i < 8; i++) {
                const int ii = (i + st) & 7;
                Bs[n0 + ii][kk] = f2b(v[ii]);
            }
        }
        __syncthreads();
#pragma unroll
        for (int kc = 0; kc < 2; kc++) {
            bf16x8 af[2], bfr[2];
#pragma unroll
            for (int mi = 0; mi < 2; mi++)
                af[mi] = *(const bf16x8*)&As[wm + mi * 16 + li][kc * 32 + quad * 8];
#pragma unroll
            for (int ni = 0; ni < 2; ni++)
                bfr[ni] = *(const bf16x8*)&Bs[wn + ni * 16 + li][kc * 32 + quad * 8];
#pragma unroll
            for (int mi = 0; mi < 2; mi++)
#pragma unroll
                for (int ni = 0; ni < 2; ni++)
                    acc[mi][ni] = __builtin_amdgcn_mfma_f32_16x16x32_bf16(
                        af[mi], bfr[ni], acc[mi][ni], 0, 0, 0);
        }
        __syncthreads();
    }

    if (mode == 1) {
        bf16* kb = z ? kb1 : kb0;
#pragma unroll
        for (int mi = 0; mi < 2; mi++)
#pragma unroll
            for (int r = 0; r < 4; r++) {
                const int row = bm + wm + mi * 16 + quad * 4 + r;
#pragma unroll
                for (int ni = 0; ni < 2; ni++) {
                    const int col = bn + wn + ni * 16 + li;
                    const float v = acc[mi][ni][r];
                    if (col < 1024)
                        kb[(size_t)row * 1024 + col] = f2b(v);
                    else
                        kb[(size_t)1024 * R + (size_t)(col - 1024) * R + row] = f2b(v);
                }
            }
        return;
    }

#pragma unroll
    for (int mi = 0; mi < 2; mi++)
#pragma unroll
        for (int r = 0; r < 4; r++) {
            const int row = bm + wm + mi * 16 + quad * 4 + r;
#pragma unroll
            for (int ni = 0; ni < 2; ni++) {
                const int col = bn + wn + ni * 16 + li;
                float v = acc[mi][ni][r];
                if (bias) v += ldx(bias, col, isb);
                if (res)  v += ldx(res, roz + (size_t)row * N + col, resb);
                stx(C, coz + (size_t)row * N + col, cb, v);
            }
        }
}

// ---------------------------------------------------------------------------
// attn_flash: round-0 verified 1-wave body. Used by the fallback path.
// ---------------------------------------------------------------------------
__global__ __launch_bounds__(64) void attn_flash(
    const bf16* __restrict__ qb, const bf16* __restrict__ kv0,
    const bf16* __restrict__ kv1,
    const void* __restrict__ rel_emb, bf16* __restrict__ out,
    long qo_bs, long out_bs, int m, int rel_off, const int* __restrict__ flagp) {

    const float SC = 0.125f * 1.44269504f;
    const bool isb = (*flagp != 0);
    const int id = blockIdx.x;
    const int xcd = id & 7;
    const int slot = id >> 3;
    const int c = (slot >> 6) * 8 + xcd;
    const int h = c & 15, z = c >> 4;
    const int q0 = (slot & 63) * 32;
    const int t = threadIdx.x;
    const int li = t & 15, quad = t >> 4;

    const bf16* qz = qb + (size_t)z * qo_bs;
    bf16* oz = out + (size_t)z * out_bs;
    const bf16* kb = z ? kv1 : kv0;
    const bf16* vtb = kb + (size_t)m * 1024;

    __shared__ float bias_s[32];
    __shared__ float tab[2080];
    __shared__ bf16 Ps[16][40];

    if (t < 32) bias_s[t] = ldx(rel_emb, t * 16 + h, isb) * SC - 40.0f;
    __syncthreads();

    const int tsz = m + 31;
    for (int i = t; i < tsz; i += 64) {
        const int rel = i - 31 - q0 + rel_off;
        const int ab = rel < 0 ? -rel : rel;
        int bucket = rel >= 0 ? 16 : 0;
        if (ab < 8) {
            bucket += ab;
        } else {
            const int p = 31 - __clz(ab);
            const int k2 = 2 * p + ((ab * ab >= (1 << (2 * p + 1))) ? 1 : 0);
            const int val = k2 + 2;
            bucket += (val > 15) ? 15 : val;
        }
        tab[i] = bias_s[bucket];
    }
    __syncthreads();

    bf16x8 aq[2][2];
#pragma unroll
    for (int g = 0; g < 2; g++)
#pragma unroll
        for (int kc = 0; kc < 2; kc++)
            aq[g][kc] = *(const bf16x8*)(qz + (size_t)(q0 + g * 16 + li) * 1024
                                         + h * 64 + kc * 32 + quad * 8);

    bf16x8 ones;
#pragma unroll
    for (int j = 0; j < 8; j++) ((short*)&ones)[j] = 0x3F80;

    f32x4 o[2][4], lac[2];
#pragma unroll
    for (int g = 0; g < 2; g++) {
#pragma unroll
        for (int r = 0; r < 4; r++) lac[g][r] = 0.f;
#pragma unroll
        for (int nb = 0; nb < 4; nb++)
#pragma unroll
            for (int r = 0; r < 4; r++) o[g][nb][r] = 0.f;
    }

    for (int j0 = 0; j0 < m; j0 += 32) {
        bf16x8 kf[4], vf[4];
#pragma unroll
        for (int nb = 0; nb < 2; nb++)
#pragma unroll
            for (int kc = 0; kc < 2; kc++)
                kf[nb * 2 + kc] = *(const bf16x8*)(
                    kb + (size_t)(j0 + nb * 16 + li) * 1024 + h * 64 + kc * 32 + quad * 8);
#pragma unroll
        for (int nb = 0; nb < 4; nb++)
            vf[nb] = *(const bf16x8*)(
                vtb + (size_t)(h * 64 + nb * 16 + li) * m + j0 + quad * 8);

#pragma unroll
        for (int g = 0; g < 2; g++) {
            f32x4 s[2];
            __builtin_amdgcn_s_setprio(1);
#pragma unroll
            for (int nb = 0; nb < 2; nb++) {
                f32x4 a;
#pragma unroll
                for (int r = 0; r < 4; r++) a[r] = 0.f;
#pragma unroll
                for (int kc = 0; kc < 2; kc++)
                    a = __builtin_amdgcn_mfma_f32_16x16x32_bf16(aq[g][kc], kf[nb * 2 + kc],
                                                                a, 0, 0, 0);
                s[nb] = a;
            }
            __builtin_amdgcn_s_setprio(0);
#pragma unroll
            for (int nb = 0; nb < 2; nb++)
#pragma unroll
                for (int r = 0; r < 4; r++) {
                    const int ti = j0 + nb * 16 + li + 31 - (g * 16 + quad * 4 + r);
                    s[nb][r] = exp2f(fmaf(s[nb][r], SC, tab[ti]));
                }
#pragma unroll
            for (int nb = 0; nb < 2; nb++)
#pragma unroll
                for (int r = 0; r < 4; r++)
                    Ps[quad * 4 + r][nb * 16 + li] = f2b(s[nb][r]);
            const bf16x8 ap = *(const bf16x8*)&Ps[li][quad * 8];
            __builtin_amdgcn_s_setprio(1);
#pragma unroll
            for (int nb = 0; nb < 4; nb++)
                o[g][nb] = __builtin_amdgcn_mfma_f32_16x16x32_bf16(ap, vf[nb],
                                                                   o[g][nb], 0, 0, 0);
            lac[g] = __builtin_amdgcn_mfma_f32_16x16x32_bf16(ap, ones, lac[g], 0, 0, 0);
            __builtin_amdgcn_s_setprio(0);
        }
    }

#pragma unroll
    for (int g = 0; g < 2; g++)
#pragma unroll
        for (int r = 0; r < 4; r++) {
            const float inv = 1.0f / lac[g][r];
            const int qi = q0 + g * 16 + quad * 4 + r;
#pragma unroll
            for (int nb = 0; nb < 4; nb++)
                oz[(size_t)qi * 1024 + h * 64 + nb * 16 + li] = f2b(o[g][nb][r] * inv);
        }
}

// ---------------------------------------------------------------------------
// ROUND 18: attn_flash64 + register double-buffer prefetch. Round 17 showed
// 64 q/wave wins (126 vs 136.5) but sits at 1 wave/SIMD with VALUBusy 38 +
// MfmaUtil 12 = ~50% dependency stall and ZERO TLP — the regime where ILP
// prefetch (neutral in round 4 under 8 waves/CU) actually applies: overlap
// must come from within the wave. kA/vA <-> kB/vB alternate; next tile's 8
// loads issue before current tile's compute. Tile ORDER unchanged ->
// bitwise-identical output. VGPR +32 (~144), irrelevant at 1 wave/SIMD.
// Falsification: SA >= 125.9 -> stall is the exp2/LDS chain; revert+converge.
// ---------------------------------------------------------------------------
__global__ __launch_bounds__(256) void attn_flash64(
    const bf16* __restrict__ qb, const bf16* __restrict__ kv0,
    const bf16* __restrict__ kv1,
    const void* __restrict__ rel_emb, bf16* __restrict__ out,
    long qo_bs, long out_bs, int m, int rel_off, const int* __restrict__ flagp) {

    const float SC = 0.125f * 1.44269504f;
    const bool isb = (*flagp != 0);
    const int t256 = threadIdx.x;
    const int w = t256 >> 6;                  // wave id 0..3
    const int t = t256 & 63;                  // lane
    const int id = (int)blockIdx.x * 4 + w;   // 0..1023
    const int xcd = id & 7;
    const int slot = id >> 3;                 // 0..127
    const int c = (slot >> 5) * 8 + xcd;      // 0..31
    const int h = c & 15, z = c >> 4;
    const int q0 = (slot & 31) * 64;          // 64-query tiles
    const int li = t & 15, quad = t >> 4;

    const bf16* qz = qb + (size_t)z * qo_bs;
    bf16* oz = out + (size_t)z * out_bs;
    const bf16* kb = z ? kv1 : kv0;
    const bf16* vtb = kb + (size_t)m * 1024;

    // Per-wave private LDS slices (no block barriers anywhere).
    __shared__ float tabS[4][2112];           // covers m+63 <= 2111
    __shared__ float biasS[4][32];
    __shared__ bf16  PsS[4][16][40];
    float* tab = tabS[w];
    float* bias_s = biasS[w];
    bf16 (*Ps)[40] = PsS[w];

    if (t < 32) bias_s[t] = ldx(rel_emb, t * 16 + h, isb) * SC - 40.0f;
    // wave-internal LDS RAW: compiler-inserted lgkmcnt (verified Ps pattern)

    const int tsz = m + 63;
    for (int i = t; i < tsz; i += 64) {
        const int rel = i - 63 - q0 + rel_off;
        const int ab = rel < 0 ? -rel : rel;
        int bucket = rel >= 0 ? 16 : 0;
        if (ab < 8) {
            bucket += ab;
        } else {
            const int p = 31 - __clz(ab);
            const int k2 = 2 * p + ((ab * ab >= (1 << (2 * p + 1))) ? 1 : 0);
            const int val = k2 + 2;
            bucket += (val > 15) ? 15 : val;
        }
        tab[i] = bias_s[bucket];
    }

    bf16x8 aq[4][2];
#pragma unroll
    for (int g = 0; g < 4; g++)
#pragma unroll
        for (int kc = 0; kc < 2; kc++)
            aq[g][kc] = *(const bf16x8*)(qz + (size_t)(q0 + g * 16 + li) * 1024
                                         + h * 64 + kc * 32 + quad * 8);

    bf16x8 ones;
#pragma unroll
    for (int j = 0; j < 8; j++) ((short*)&ones)[j] = 0x3F80;

    f32x4 o[4][4], lac[4];
#pragma unroll
    for (int g = 0; g < 4; g++) {
#pragma unroll
        for (int r = 0; r < 4; r++) lac[g][r] = 0.f;
#pragma unroll
        for (int nb = 0; nb < 4; nb++)
#pragma unroll
            for (int r = 0; r < 4; r++) o[g][nb][r] = 0.f;
    }

// Load one 32-key K/V tile at key offset J into register sets KF[4]/VF[4].
#define LOADKV(KF, VF, J)                                                      \
    {                                                                          \
        _Pragma("unroll")                                                      \
        for (int nb = 0; nb < 2; nb++)                                         \
            _Pragma("unroll")                                                  \
            for (int kc = 0; kc < 2; kc++)                                     \
                KF[nb * 2 + kc] = *(const bf16x8*)(                            \
                    kb + (size_t)((J) + nb * 16 + li) * 1024 + h * 64          \
                    + kc * 32 + quad * 8);                                     \
        _Pragma("unroll")                                                      \
        for (int nb = 0; nb < 4; nb++)                                         \
            VF[nb] = *(const bf16x8*)(                                         \
                vtb + (size_t)(h * 64 + nb * 16 + li) * m + (J) + quad * 8);   \
    }

// Process one 32-key tile over all 4 q-groups at key offset J0.
#define ABODY(KF, VF, J0)                                                      \
    {                                                                          \
        _Pragma("unroll")                                                      \
        for (int g = 0; g < 4; g++) {                                          \
            f32x4 s[2];                                                        \
            __builtin_amdgcn_s_setprio(1);                                     \
            _Pragma("unroll")                                                  \
            for (int nb = 0; nb < 2; nb++) {                                   \
                f32x4 a;                                                       \
                _Pragma("unroll")                                              \
                for (int r = 0; r < 4; r++) a[r] = 0.f;                        \
                _Pragma("unroll")                                              \
                for (int kc = 0; kc < 2; kc++)                                 \
                    a = __builtin_amdgcn_mfma_f32_16x16x32_bf16(               \
                        aq[g][kc], KF[nb * 2 + kc], a, 0, 0, 0);               \
                s[nb] = a;                                                     \
            }                                                                  \
            __builtin_amdgcn_s_setprio(0);                                     \
            _Pragma("unroll")                                                  \
            for (int nb = 0; nb < 2; nb++)                                     \
                _Pragma("unroll")                                              \
                for (int r = 0; r < 4; r++) {                                  \
                    const int ti = (J0) + nb * 16 + li + 63                    \
                                   - (g * 16 + quad * 4 + r);                  \
                    s[nb][r] = exp2f(fmaf(s[nb][r], SC, tab[ti]));             \
                }                                                              \
            _Pragma("unroll")                                                  \
            for (int nb = 0; nb < 2; nb++)                                     \
                _Pragma("unroll")                                              \
                for (int r = 0; r < 4; r++)                                    \
                    Ps[quad * 4 + r][nb * 16 + li] = f2b(s[nb][r]);            \
            const bf16x8 ap = *(const bf16x8*)&Ps[li][quad * 8];               \
            __builtin_amdgcn_s_setprio(1);                                     \
            _Pragma("unroll")                                                  \
            for (int nb = 0; nb < 4; nb++)                                     \
                o[g][nb] = __builtin_amdgcn_mfma_f32_16x16x32_bf16(            \
                    ap, VF[nb], o[g][nb], 0, 0, 0);                            \
            lac[g] = __builtin_amdgcn_mfma_f32_16x16x32_bf16(                  \
                ap, ones, lac[g], 0, 0, 0);                                    \
            __builtin_amdgcn_s_setprio(0);                                     \
        }                                                                      \
    }

    bf16x8 kA[4], vA[4], kB[4], vB[4];
    LOADKV(kA, vA, 0);
    for (int j0 = 0; j0 < m; j0 += 64) {       // m is a multiple of 64
        LOADKV(kB, vB, j0 + 32);               // prefetch second half-tile
        ABODY(kA, vA, j0);
        const int jn = (j0 + 64 < m) ? (j0 + 64) : 0;   // harmless re-load at end
        LOADKV(kA, vA, jn);                    // prefetch next tile
        ABODY(kB, vB, j0 + 32);
    }

#undef LOADKV
#undef ABODY

#pragma unroll
    for (int g = 0; g < 4; g++)
#pragma unroll
        for (int r = 0; r < 4; r++) {
            const float inv = 1.0f / lac[g][r];
            const int qi = q0 + g * 16 + quad * 4 + r;
#pragma unroll
            for (int nb = 0; nb < 4; nb++)
                oz[(size_t)qi * 1024 + h * 64 + nb * 16 + li] = f2b(o[g][nb][r] * inv);
        }
}

// ---------------------------------------------------------------------------
// Launcher. Fast path (ws >= 56 MB + 256; measured ws = 256 MB):
//   F_A|F_B|F_C (24 MB) + WT (8) + F_X (8) + F_Y (6) + WT2 (8) = 54 MB.
// Round-17 schedule (best: 440.7 µs) with attn_flash64 + reg prefetch.
// Fallback: round-7 plan (24 MB).
// ---------------------------------------------------------------------------
extern "C" void kernel_launch(void* const* d_in, const int* in_sizes, int n_in,
                              void* d_out, int out_size, void* d_ws, size_t ws_size,
                              hipStream_t stream) {
    const long M1 = 1024 * 1024;
    const long M2 = 2 * 1024 * 1024;
    const long M4 = 4 * 1024 * 1024;
    if (ws_size < 24u * 1024 * 1024 + 256) return;

    const void* x      = d_in[0];
    const void* ctx    = d_in[1];
    const void* sa_ng  = d_in[2];
    const void* sa_nb  = d_in[3];
    const void* sa_ncg = d_in[4];
    const void* sa_ncb = d_in[5];
    const void* sa_wq  = d_in[6];
    const void* sa_wkv = d_in[7];
    const void* sa_wo  = d_in[8];
    const void* sa_bo  = d_in[9];
    const void* sa_rel = d_in[10];
    const void* ca_ng  = d_in[11];
    const void* ca_nb  = d_in[12];
    const void* ca_ncg = d_in[13];
    const void* ca_ncb = d_in[14];
    const void* ca_wq  = d_in[15];
    const void* ca_wkv = d_in[16];
    const void* ca_wo  = d_in[17];
    const void* ca_bo  = d_in[18];
    const void* ca_rel = d_in[19];

    int* flag = (int*)d_ws;
    bf16* F_A = (bf16*)((char*)d_ws + 256);
    bf16* F_B = F_A + M4;
    bf16* F_C = F_B + M4;
    bf16* WT  = F_C + M4;                // fast path only (SA weights)
    bf16* F_X = WT + M4;                 // fast path only (xn buffer)
    bf16* F_Y = F_X + M4;                // fast path only (ctx-LN + CA K/V)
    bf16* WT2 = F_Y + 3 * M1;            // fast path only (CA weights)
    bf16* qd  = (bf16*)d_out;            // d_out as bf16 scratch (q / ao)

    sniff_kernel<<<1, 256, 0, stream>>>(x, flag);

    if (ws_size >= 56u * 1024 * 1024 + 256) {
        bf16* WTq  = WT;                 // [1024][1024]
        bf16* WTkv = WT + M1;            // [2048][1024]
        bf16* WTo  = WT + 3 * M1;        // [1024][1024]
        bf16* WT2q  = WT2;
        bf16* WT2kv = WT2 + M1;
        bf16* WT2o  = WT2 + 3 * M1;
        bf16* CAK0 = F_Y + M1;           // z0: K[512][1024] + V^T[1024][512]
        bf16* CAK1 = F_Y + 2 * M1;       // z1: same layout

        // ===== prologue: weight transposes + both input LNs (ONE dispatch)
        prologue_kernel<<<dim3(7168), 256, 0, stream>>>(
            sa_wq, sa_wkv, sa_wo, ca_wq, ca_wkv, ca_wo,
            WTq, WTkv, WTo, WT2q, WT2kv, WT2o,
            x, ctx, sa_ng, sa_nb, sa_ncg, sa_ncb, ca_ncg, ca_ncb,
            F_X, F_B, F_Y, flag);

        // ===== BIG (128^2): SA-q + SA-kv + CA-kv =====
        {
            GArgs gq = {};
            gq.A = F_X; gq.Bt = WTq; gq.C = qd;
            gq.N = 1024; gq.nbx = 8; gq.nby = 32;
            GArgs gkv = {};
            gkv.A = F_B; gkv.Bt = WTkv;
            gkv.N = 2048; gkv.mode = 1; gkv.zsplit = 2048; gkv.zrows = 2048;
            gkv.kb0 = F_A; gkv.kb1 = F_C; gkv.nbx = 16; gkv.nby = 32;
            GArgs gca = {};
            gca.A = F_Y; gca.Bt = WT2kv;
            gca.N = 2048; gca.mode = 1; gca.zsplit = 512; gca.zrows = 512;
            gca.kb0 = CAK0; gca.kb1 = CAK1; gca.nbx = 16; gca.nby = 8;
            gemm_fused<<<dim3(40, 32), 256, 0, stream>>>(gq, gkv, gca, flag);
        }

        // ===== self-attention + o-proj =====
        attn_flash64<<<dim3(256), 256, 0, stream>>>(
            qd, F_A, F_C, sa_rel, qd, M2, M2, 2048, 0, flag);
        gemm_t64<<<dim3(16, 64), 256, 0, stream>>>(
            qd, WTo, F_B, 0, sa_bo, x, 1, 1024, flag);

        // ===== cross-attention =====
        ln_dual_kernel<<<dim3(2048, 1, 2), 256, 0, stream>>>(
            F_B, 0, M2, 0, ca_ng, ca_nb, nullptr, nullptr, F_X, nullptr, M2, flag);
        gemm_t64<<<dim3(16, 64), 256, 0, stream>>>(
            F_X, WT2q, qd, 0, nullptr, nullptr, 0, 1024, flag);
        attn_flash64<<<dim3(256), 256, 0, stream>>>(
            qd, CAK0, CAK1, ca_rel, F_C, M2, M2, 512, 1536, flag);
        gemm_t64<<<dim3(16, 64), 256, 0, stream>>>(
            F_C, WT2o, d_out, 1, ca_bo, F_B, 0, 1024, flag);
        return;
    }

    // ================= fallback: round-7 verified plan =================
    ln_dual_kernel<<<dim3(2048, 1, 2), 256, 0, stream>>>(
        x, 0, M2, 1, sa_ng, sa_nb, sa_ncg, sa_ncb, F_A, F_B, M2, flag);
    gemm_mfma<<<dim3(16, 32, 2), 256, 0, stream>>>(
        F_A, M2, sa_wq, qd, 0, M2, 0, nullptr, nullptr, 0, 0, 0,
        1024, 1024, 0, 0, nullptr, nullptr, flag);
    gemm_mfma<<<dim3(32, 32, 2), 256, 0, stream>>>(
        F_B, M2, sa_wkv, nullptr, 0, 0, 0, nullptr, nullptr, 0, 0, 0,
        1024, 2048, 1, 2048, F_A, F_C, flag);
    attn_flash<<<dim3(2048), 64, 0, stream>>>(
        qd, F_A, F_C, sa_rel, qd, M2, M2, 2048, 0, flag);
    gemm_mfma<<<dim3(16, 32, 2), 256, 0, stream>>>(
        qd, M2, sa_wo, F_B, 0, M2, 0, sa_bo, x, 0, M2, 1,
        1024, 1024, 0, 0, nullptr, nullptr, flag);

    ln_dual_kernel<<<dim3(2048, 1, 2), 256, 0, stream>>>(
        F_B, 0, M2, 0, ca_ng, ca_nb, nullptr, nullptr, F_A, nullptr, M2, flag);
    ln_dual_kernel<<<dim3(512, 1, 2), 256, 0, stream>>>(
        ctx, 0, 512 * 1024, 1, ca_ncg, ca_ncb, nullptr, nullptr,
        F_C, nullptr, 512 * 1024, flag);
    gemm_mfma<<<dim3(16, 32, 2), 256, 0, stream>>>(
        F_A, M2, ca_wq, qd, 0, M2, 0, nullptr, nullptr, 0, 0, 0,
        1024, 1024, 0, 0, nullptr, nullptr, flag);
    gemm_mfma<<<dim3(32, 8, 2), 256, 0, stream>>>(
        F_C, 512 * 1024, ca_wkv, nullptr, 0, 0, 0, nullptr, nullptr, 0, 0, 0,
        1024, 2048, 1, 512, F_A, F_A + M1, flag);
    attn_flash<<<dim3(2048), 64, 0, stream>>>(
        qd, F_A, F_A + M1, ca_rel, F_C, M2, M2, 512, 1536, flag);
    gemm_mfma<<<dim3(16, 32, 2), 256, 0, stream>>>(
        F_C, M2, ca_wo, d_out, 0, M2, 1, ca_bo, F_B, 0, M2, 0,
        1024, 1024, 0, 0, nullptr, nullptr, flag);
}